// Round 1
// baseline (3152.839 us; speedup 1.0000x reference)
//
#include <hip/hip_runtime.h>
#include <math.h>

constexpr int Bn = 8, Cn = 64, Hn = 128, Wn = 128;
constexpr int HW  = Hn * Wn;      // 16384
constexpr int CHW = Cn * HW;      // 1048576

// ---------------- elementwise add: A = f_event + f_blur ----------------
__global__ void add_k(const float4* __restrict__ a, const float4* __restrict__ b,
                      float4* __restrict__ o, int n4) {
    int i = blockIdx.x * blockDim.x + threadIdx.x;
    if (i < n4) {
        float4 x = a[i], y = b[i];
        o[i] = make_float4(x.x + y.x, x.y + y.y, x.z + y.z, x.w + y.w);
    }
}

// ---------------- conv3x3, C=64->64, zero pad=1 ----------------
// 16x16 pixel tile / block (256 threads, 1 px/thread), input channels chunked
// by 16 through LDS, acc[64] in registers (all out channels).
template<bool RELU, bool BIAS, bool ADD_INPUT>
__global__ __launch_bounds__(256) void conv3x3_k(const float* __restrict__ in,
                                                 const float* __restrict__ Wt,
                                                 const float* __restrict__ bias,
                                                 float* __restrict__ out) {
    __shared__ float tile[16 * 324];                  // 16 ci x 18x18, 20.7 KB
    const int b  = blockIdx.z;
    const int by = blockIdx.y << 4, bx = blockIdx.x << 4;
    const int tid = threadIdx.x, tx = tid & 15, ty = tid >> 4;
    const float* inb = in + (size_t)b * CHW;

    float acc[64];
#pragma unroll
    for (int u = 0; u < 64; ++u) acc[u] = 0.f;

    for (int cc = 0; cc < 64; cc += 16) {
        __syncthreads();
        for (int idx = tid; idx < 16 * 324; idx += 256) {
            int ci = idx / 324;
            int p  = idx - ci * 324;
            int yy = p / 18, xx = p - yy * 18;
            int gy = by + yy - 1, gx = bx + xx - 1;
            float v = 0.f;
            if ((unsigned)gy < (unsigned)Hn && (unsigned)gx < (unsigned)Wn)
                v = inb[(cc + ci) * HW + gy * Wn + gx];
            tile[idx] = v;
        }
        __syncthreads();
#pragma unroll 1
        for (int ci = 0; ci < 16; ++ci) {
            const int tb = ci * 324 + ty * 18 + tx;
            const float p00 = tile[tb],      p01 = tile[tb + 1],  p02 = tile[tb + 2];
            const float p10 = tile[tb + 18], p11 = tile[tb + 19], p12 = tile[tb + 20];
            const float p20 = tile[tb + 36], p21 = tile[tb + 37], p22 = tile[tb + 38];
            const float* wp = Wt + (cc + ci) * 9;
#pragma unroll
            for (int co = 0; co < 64; ++co) {
                const float* w = wp + co * 576;
                float s = p00 * w[0];
                s = fmaf(p01, w[1], s); s = fmaf(p02, w[2], s);
                s = fmaf(p10, w[3], s); s = fmaf(p11, w[4], s);
                s = fmaf(p12, w[5], s); s = fmaf(p20, w[6], s);
                s = fmaf(p21, w[7], s); s = fmaf(p22, w[8], s);
                acc[co] += s;
            }
        }
    }
    const int y = by + ty, x = bx + tx;
    const size_t base = (size_t)b * CHW + y * Wn + x;
#pragma unroll
    for (int co = 0; co < 64; ++co) {
        float v = acc[co];
        if (BIAS) v += bias[co];
        if (RELU) v = fmaxf(v, 0.f);
        if (ADD_INPUT) v += in[base + co * HW];
        out[base + co * HW] = v;
    }
}

// ---------------- mean over H,W per (b,c) ----------------
__global__ void mean_hw_k(const float* __restrict__ in, float* __restrict__ w0) {
    int bc = blockIdx.x;                       // 0..511
    const float* p = in + (size_t)bc * HW;
    float s = 0.f;
    for (int i = threadIdx.x; i < HW; i += 256) s += p[i];
#pragma unroll
    for (int off = 32; off; off >>= 1) s += __shfl_down(s, off);
    __shared__ float ws4[4];
    if ((threadIdx.x & 63) == 0) ws4[threadIdx.x >> 6] = s;
    __syncthreads();
    if (threadIdx.x == 0)
        w0[bc] = (ws4[0] + ws4[1] + ws4[2] + ws4[3]) * (1.f / 16384.f);
}

// ---------------- SE MLP: relu(w0@A1.T+b1) -> sigmoid(@A2.T+b2) ----------------
__global__ void mlp_k(const float* __restrict__ w0, const float* __restrict__ A1,
                      const float* __restrict__ b1, const float* __restrict__ A2,
                      const float* __restrict__ b2, float* __restrict__ w0s) {
    int b = blockIdx.x, t = threadIdx.x;       // 128 threads
    __shared__ float w0r[64], hid[128];
    if (t < 64) w0r[t] = w0[b * 64 + t];
    __syncthreads();
    float s = b1[t];
    for (int c = 0; c < 64; ++c) s = fmaf(A1[t * 64 + c], w0r[c], s);
    hid[t] = fmaxf(s, 0.f);
    __syncthreads();
    if (t < 64) {
        float s2 = b2[t];
        for (int j = 0; j < 128; ++j) s2 = fmaf(A2[t * 128 + j], hid[j], s2);
        w0s[b * 64 + t] = 1.f / (1.f + expf(-s2));
    }
}

// ---------------- rgb gate: conv1x1 C->1 + bias ----------------
__global__ void rgb_k(const float* __restrict__ f2, const float* __restrict__ Rw,
                      const float* __restrict__ rb, float* __restrict__ rgb) {
    int by = blockIdx.x;                       // b*128+y
    int b = by >> 7, y = by & 127;
    int x = threadIdx.x;                       // 128
    const float* p = f2 + (size_t)b * CHW + y * Wn + x;
    float s = rb[0];
    for (int c = 0; c < 64; ++c) s = fmaf(Rw[c], p[c * HW], s);
    rgb[by * Wn + x] = s;
}

// ---------------- f_b1 = f_blur * (1+w0s) * (1+rgb) ----------------
__global__ void fb1_k(const float4* __restrict__ fblur, const float* __restrict__ w0s,
                      const float4* __restrict__ rgb, float4* __restrict__ o) {
    int i = blockIdx.x * blockDim.x + threadIdx.x;      // 0..2097151
    int b = i >> 18;
    int c = (i >> 12) & 63;
    int pix4 = i & 4095;
    float s = 1.f + w0s[b * 64 + c];
    float4 f = fblur[i];
    float4 r = rgb[(b << 12) + pix4];
    o[i] = make_float4(f.x * s * (1.f + r.x), f.y * s * (1.f + r.y),
                       f.z * s * (1.f + r.z), f.w * s * (1.f + r.w));
}

// ---------------- dynamic per-pixel 3x3 conv (edge pad) + residual ----------------
// out = fb + sum_t kern(c,t) * fb[edge-clamped patch], kern generated on the fly
// from h (64 regs/thread) through G2 (576x64) + g2b.
__global__ __launch_bounds__(256) void dynconv_k(const float* __restrict__ fb,
                                                 const float* __restrict__ h,
                                                 const float* __restrict__ G2,
                                                 const float* __restrict__ g2b,
                                                 float* __restrict__ out) {
    __shared__ float tile[16 * 324];
    const int b  = blockIdx.z;
    const int by = blockIdx.y << 4, bx = blockIdx.x << 4;
    const int tid = threadIdx.x, tx = tid & 15, ty = tid >> 4;
    const int y = by + ty, x = bx + tx;

    float hr[64];
    const float* hp = h + (size_t)b * CHW + y * Wn + x;
#pragma unroll
    for (int ci = 0; ci < 64; ++ci) hr[ci] = hp[ci * HW];

    const float* fbb = fb + (size_t)b * CHW;
    for (int cc = 0; cc < 64; cc += 16) {
        __syncthreads();
        for (int idx = tid; idx < 16 * 324; idx += 256) {
            int ci = idx / 324;
            int p  = idx - ci * 324;
            int yy = p / 18, xx = p - yy * 18;
            int gy = min(max(by + yy - 1, 0), Hn - 1);
            int gx = min(max(bx + xx - 1, 0), Wn - 1);
            tile[idx] = fbb[(cc + ci) * HW + gy * Wn + gx];
        }
        __syncthreads();
#pragma unroll 1
        for (int c0 = 0; c0 < 16; ++c0) {
            const int c = cc + c0;
            float kv[9];
            const float* gb = g2b + c * 9;
#pragma unroll
            for (int t = 0; t < 9; ++t) kv[t] = gb[t];
            const float* g = G2 + (size_t)c * 9 * 64;
#pragma unroll
            for (int ci = 0; ci < 64; ++ci) {
                const float hv = hr[ci];
#pragma unroll
                for (int t = 0; t < 9; ++t) kv[t] = fmaf(g[t * 64 + ci], hv, kv[t]);
            }
            const int tb = c0 * 324 + ty * 18 + tx;
            float s = kv[0] * tile[tb]      + kv[1] * tile[tb + 1]  + kv[2] * tile[tb + 2]
                    + kv[3] * tile[tb + 18] + kv[4] * tile[tb + 19] + kv[5] * tile[tb + 20]
                    + kv[6] * tile[tb + 36] + kv[7] * tile[tb + 37] + kv[8] * tile[tb + 38];
            out[(size_t)b * CHW + c * HW + y * Wn + x] = tile[tb + 19] + s;
        }
    }
}

// ---------------- channel max/mean -> comp[B,2,H,W] ----------------
__global__ void comp_k(const float* __restrict__ sa, float* __restrict__ comp) {
    int by = blockIdx.x;
    int b = by >> 7, y = by & 127;
    int x = threadIdx.x;
    const float* p = sa + (size_t)b * CHW + y * Wn + x;
    float mx = p[0], sm = p[0];
    for (int c = 1; c < 64; ++c) { float v = p[c * HW]; mx = fmaxf(mx, v); sm += v; }
    float* cb = comp + (size_t)b * 2 * HW + y * Wn + x;
    cb[0]  = mx;
    cb[HW] = sm * (1.f / 64.f);
}

// ---------------- spatial 5x5 conv (2->1, pad 2, zero) + sigmoid ----------------
__global__ void sconv5_k(const float* __restrict__ comp, const float* __restrict__ Ew,
                         const float* __restrict__ eb, float* __restrict__ scale) {
    int id = blockIdx.x * 256 + threadIdx.x;   // 0..131071
    int b = id >> 14, p = id & 16383;
    int y = p >> 7, x = p & 127;
    const float* cb = comp + (size_t)b * 2 * HW;
    float acc = eb[0];
#pragma unroll
    for (int ch = 0; ch < 2; ++ch)
#pragma unroll
        for (int ky = 0; ky < 5; ++ky) {
            int gy = y + ky - 2;
            if ((unsigned)gy >= (unsigned)Hn) continue;
#pragma unroll
            for (int kx = 0; kx < 5; ++kx) {
                int gx = x + kx - 2;
                if ((unsigned)gx >= (unsigned)Wn) continue;
                acc = fmaf(Ew[ch * 25 + ky * 5 + kx], cb[ch * HW + gy * Wn + gx], acc);
            }
        }
    scale[id] = 1.f / (1.f + expf(-acc));
}

// ---------------- final fusion: out = Fw @ concat(f_event*(1+scale), f_b2) ----------------
__global__ __launch_bounds__(256) void fuse_k(const float* __restrict__ fe,
                                              const float* __restrict__ scale,
                                              const float* __restrict__ fb2,
                                              const float* __restrict__ Fw,
                                              float* __restrict__ out) {
    __shared__ float tile[128 * 64];           // 32 KB: 128 ch x 64 px
    const int blk = blockIdx.x;                // 0..2047
    const int b = blk >> 8;
    const int seg = blk & 255;
    const int pix0 = seg << 6;
    const int tid = threadIdx.x;
    const float* feb = fe  + (size_t)b * CHW + pix0;
    const float* fbb = fb2 + (size_t)b * CHW + pix0;
    const float* sc  = scale + b * HW + pix0;
    for (int idx = tid; idx < 8192; idx += 256) {
        int ci = idx >> 6, px = idx & 63;
        float v;
        if (ci < 64) v = feb[ci * HW + px] * (1.f + sc[px]);
        else         v = fbb[(ci - 64) * HW + px];
        tile[idx] = v;
    }
    __syncthreads();
    const int px = tid & 63, og = tid >> 6;    // og wave-uniform
    float acc[32];
#pragma unroll
    for (int u = 0; u < 32; ++u) acc[u] = 0.f;
    const float* w = Fw + og * 32 * 128;
#pragma unroll 1
    for (int i = 0; i < 128; ++i) {
        float v = tile[i * 64 + px];
#pragma unroll
        for (int u = 0; u < 32; ++u) acc[u] = fmaf(w[u * 128 + i], v, acc[u]);
    }
    float* ob = out + (size_t)b * 2 * CHW + og * 32 * HW + pix0 + px;
#pragma unroll
    for (int u = 0; u < 32; ++u) ob[u * HW] = acc[u];
}

// ---------------- host launch ----------------
extern "C" void kernel_launch(void* const* d_in, const int* in_sizes, int n_in,
                              void* d_out, int out_size, void* d_ws, size_t ws_size,
                              hipStream_t stream) {
    const float* f_event = (const float*)d_in[0];
    const float* f_blur  = (const float*)d_in[1];
    const float* Wt1 = (const float*)d_in[2];
    const float* Wt2 = (const float*)d_in[3];
    const float* Wt3 = (const float*)d_in[4];
    const float* A1  = (const float*)d_in[5];
    const float* b1  = (const float*)d_in[6];
    const float* A2  = (const float*)d_in[7];
    const float* b2  = (const float*)d_in[8];
    const float* G1  = (const float*)d_in[9];
    const float* g1b = (const float*)d_in[10];
    const float* G2  = (const float*)d_in[11];
    const float* g2b = (const float*)d_in[12];
    const float* Rw  = (const float*)d_in[13];
    const float* rb  = (const float*)d_in[14];
    const float* S1  = (const float*)d_in[15];
    const float* S2  = (const float*)d_in[16];
    const float* Ew  = (const float*)d_in[17];
    const float* eb  = (const float*)d_in[18];
    const float* Fw  = (const float*)d_in[19];
    float* out = (float*)d_out;

    float* ws   = (float*)d_ws;
    float* bufA = ws;                          // 8388608 floats each
    float* bufB = ws + (size_t)Bn * CHW;
    float* bufC = ws + (size_t)2 * Bn * CHW;
    float* w0    = ws + (size_t)3 * Bn * CHW;  // 512
    float* w0s   = w0 + 512;                   // 512
    float* rgb   = w0s + 512;                  // 131072
    float* comp  = rgb + Bn * HW;              // 262144
    float* scale = comp + 2 * Bn * HW;         // 131072

    dim3 cgrid(Wn / 16, Hn / 16, Bn);          // 8x8x8
    const int n4 = Bn * CHW / 4;               // 2097152

    // 1. fused0 = f_event + f_blur
    add_k<<<n4 / 256, 256, 0, stream>>>((const float4*)f_event, (const float4*)f_blur,
                                        (float4*)bufA, n4);
    // 2. B = relu(conv(A, Wt1))
    conv3x3_k<true, false, false><<<cgrid, 256, 0, stream>>>(bufA, Wt1, nullptr, bufB);
    // 3. A = conv(B, Wt2)  -> "fused"
    conv3x3_k<false, false, false><<<cgrid, 256, 0, stream>>>(bufB, Wt2, nullptr, bufA);
    // 4. SE gate
    mean_hw_k<<<Bn * Cn, 256, 0, stream>>>(bufA, w0);
    mlp_k<<<Bn, 128, 0, stream>>>(w0, A1, b1, A2, b2, w0s);
    // 5. B = A + relu(conv(A, Wt3)) -> fused2
    conv3x3_k<true, false, true><<<cgrid, 256, 0, stream>>>(bufA, Wt3, nullptr, bufB);
    // 6. rgb gate from fused2
    rgb_k<<<Bn * Hn, Wn, 0, stream>>>(bufB, Rw, rb, rgb);
    // 7. C = f_blur * (1+w0s) * (1+rgb)  -> f_b1
    fb1_k<<<n4 / 256, 256, 0, stream>>>((const float4*)f_blur, w0s,
                                        (const float4*)rgb, (float4*)bufC);
    // 8. A = relu(conv(f_event, G1) + g1b)  -> h
    conv3x3_k<true, true, false><<<cgrid, 256, 0, stream>>>(f_event, G1, g1b, bufA);
    // 9. B = C + dynconv(C, kern(A))  -> f_b2
    dynconv_k<<<cgrid, 256, 0, stream>>>(bufC, bufA, G2, g2b, bufB);
    // 10. sa = conv(relu(conv(f_event,S1)), S2)
    conv3x3_k<true, false, false><<<cgrid, 256, 0, stream>>>(f_event, S1, nullptr, bufA);
    conv3x3_k<false, false, false><<<cgrid, 256, 0, stream>>>(bufA, S2, nullptr, bufC);
    // 11. comp + 5x5 conv + sigmoid -> scale_e
    comp_k<<<Bn * Hn, Wn, 0, stream>>>(bufC, comp);
    sconv5_k<<<Bn * HW / 256, 256, 0, stream>>>(comp, Ew, eb, scale);
    // 12. out = Fw @ concat(f_event*(1+scale_e), f_b2)
    fuse_k<<<Bn * HW / 64, 256, 0, stream>>>(f_event, scale, bufB, Fw, out);
}

// Round 3
// 977.229 us; speedup vs baseline: 3.2263x; 3.2263x over previous
//
#include <hip/hip_runtime.h>
#include <math.h>

constexpr int Bn = 8, Cn = 64, Hn = 128, Wn = 128;
constexpr int HW  = Hn * Wn;      // 16384
constexpr int CHW = Cn * HW;      // 1048576

typedef float  f32x4  __attribute__((ext_vector_type(4)));
typedef __bf16 bf16x8 __attribute__((ext_vector_type(8)));
typedef unsigned int u32x4 __attribute__((ext_vector_type(4)));

static __device__ __forceinline__ unsigned short f2bf(float f) {
    unsigned u = __builtin_bit_cast(unsigned, f);
    u = (u + 0x7FFF + ((u >> 16) & 1)) >> 16;
    return (unsigned short)u;
}

// ---------------- elementwise add: A = f_event + f_blur ----------------
__global__ void add_k(const float4* __restrict__ a, const float4* __restrict__ b,
                      float4* __restrict__ o, int n4) {
    int i = blockIdx.x * blockDim.x + threadIdx.x;
    if (i < n4) {
        float4 x = a[i], y = b[i];
        o[i] = make_float4(x.x + y.x, x.y + y.y, x.z + y.z, x.w + y.w);
    }
}

// ---------------- weight prep: OIHW fp32 -> [h][s][t][co][8cj] bf16 ----------------
// dst tensor stride 36864; flat dst idx = (((h*4+s)*9 + t)*64 + co)*8 + cj,
// ci = (h*4+s)*8 + cj.
__global__ void prep_w_k(const float* __restrict__ W0, const float* __restrict__ W1,
                         const float* __restrict__ W2, const float* __restrict__ W3,
                         const float* __restrict__ W4, const float* __restrict__ W5,
                         unsigned short* __restrict__ dst) {
    int i = blockIdx.x * 256 + threadIdx.x;
    if (i >= 36864) return;
    const float* W = W0;
    switch (blockIdx.y) {
        case 1: W = W1; break; case 2: W = W2; break;
        case 3: W = W3; break; case 4: W = W4; break; case 5: W = W5; break;
        default: break;
    }
    int cj = i & 7;
    int rest = i >> 3;
    int co = rest & 63;
    rest >>= 6;              // (h*4+s)*9 + t
    int t  = rest % 9;
    int hs = rest / 9;       // 0..7
    int ci = hs * 8 + cj;
    dst[(size_t)blockIdx.y * 36864 + i] = f2bf(W[(co * 64 + ci) * 9 + t]);
}

// ---------------- conv3x3 via MFMA, C=64->64, zero pad=1 ----------------
// fp32 NCHW in/out. 16x16 px tile, 4 waves: wave w = all 64 co x rows [4w,4w+4).
// K = 9 taps x 64 ci, ci chunked by 32 (two restaged halves).
// LDS input: planes [s=0..3][18y][18x][8ci] bf16 (s = ci_local>>3).
// LDS weights: planes [s][t][co][8ci] bf16, pre-transformed in global.
template<bool RELU, bool BIAS, bool ADD_INPUT>
__global__ __launch_bounds__(256, 2) void conv3x3_mfma(
        const float* __restrict__ in, const unsigned short* __restrict__ Wp,
        const float* __restrict__ bias, float* __restrict__ out) {
    __shared__ unsigned short smIn[10368];   // 4 x 324 x 8 = 20.25 KB
    __shared__ unsigned short smW[18432];    // 4 x 9 x 64 x 8 = 36 KB
    const int b  = blockIdx.z;
    const int by = blockIdx.y << 4, bx = blockIdx.x << 4;
    const int tid = threadIdx.x;
    const int lane = tid & 63, w = tid >> 6;
    const int lx = lane & 15, ls = lane >> 4;
    const float* inb = in + (size_t)b * CHW;

    f32x4 acc[4][4];
#pragma unroll
    for (int m = 0; m < 4; ++m)
#pragma unroll
        for (int n = 0; n < 4; ++n) acc[m][n] = f32x4{0.f, 0.f, 0.f, 0.f};

    for (int h = 0; h < 2; ++h) {
        __syncthreads();
        // stage input half: ci in [32h, 32h+32), pairs of planes packed as u32
        {
            const int cibase = h << 5;
            for (int idx = tid; idx < 5184; idx += 256) {
                int c2 = idx / 324;              // ci pair index 0..15
                int p  = idx - c2 * 324;         // 0..323 within 18x18
                int yy = p / 18, xx = p - yy * 18;
                int gy = by + yy - 1, gx = bx + xx - 1;
                unsigned pk = 0;
                if ((unsigned)gy < (unsigned)Hn && (unsigned)gx < (unsigned)Wn) {
                    const float* sp = inb + (size_t)(cibase + c2 * 2) * HW + gy * Wn + gx;
                    pk = (unsigned)f2bf(sp[0]) | ((unsigned)f2bf(sp[HW]) << 16);
                }
                ((unsigned*)smIn)[(c2 >> 2) * 1296 + p * 4 + (c2 & 3)] = pk;
            }
        }
        // stage weights half: straight 36 KB copy (layout matches LDS exactly)
        {
            const u32x4* src = (const u32x4*)(Wp + h * 18432);
            u32x4* dst = (u32x4*)smW;
            for (int i = tid; i < 2304; i += 256) dst[i] = src[i];
        }
        __syncthreads();

#pragma unroll
        for (int ky = 0; ky < 3; ++ky)
#pragma unroll
        for (int kx = 0; kx < 3; ++kx) {
            const int t = ky * 3 + kx;
            bf16x8 a[4];
            const unsigned short* wbase = smW + ls * 4608 + t * 512 + lx * 8;
#pragma unroll
            for (int m = 0; m < 4; ++m)
                a[m] = *(const bf16x8*)(wbase + m * 128);
            const unsigned short* ibase =
                smIn + ls * 2592 + (((4 * w + ky) * 18) + lx + kx) * 8;
#pragma unroll
            for (int n = 0; n < 4; ++n) {
                bf16x8 bf = *(const bf16x8*)(ibase + n * 144);
#pragma unroll
                for (int m = 0; m < 4; ++m)
                    acc[m][n] = __builtin_amdgcn_mfma_f32_16x16x32_bf16(
                        a[m], bf, acc[m][n], 0, 0, 0);
            }
        }
    }

    // epilogue: D col = lane&15 -> x, row = (lane>>4)*4+r -> co within frag
    const int y0 = by + 4 * w;
    const size_t outb = (size_t)b * CHW;
#pragma unroll
    for (int m = 0; m < 4; ++m) {
#pragma unroll
        for (int r = 0; r < 4; ++r) {
            const int co = 16 * m + ls * 4 + r;
            float bv = 0.f;
            if constexpr (BIAS) bv = bias[co];
#pragma unroll
            for (int n = 0; n < 4; ++n) {
                float v = acc[m][n][r] + bv;
                if constexpr (RELU) v = fmaxf(v, 0.f);
                const size_t off = outb + (size_t)co * HW + (size_t)(y0 + n) * Wn + bx + lx;
                if constexpr (ADD_INPUT) v += in[off];
                out[off] = v;
            }
        }
    }
}

// ---------------- mean over H,W per (b,c) ----------------
__global__ void mean_hw_k(const float* __restrict__ in, float* __restrict__ w0) {
    int bc = blockIdx.x;
    const float* p = in + (size_t)bc * HW;
    float s = 0.f;
    for (int i = threadIdx.x; i < HW; i += 256) s += p[i];
#pragma unroll
    for (int off = 32; off; off >>= 1) s += __shfl_down(s, off);
    __shared__ float ws4[4];
    if ((threadIdx.x & 63) == 0) ws4[threadIdx.x >> 6] = s;
    __syncthreads();
    if (threadIdx.x == 0)
        w0[bc] = (ws4[0] + ws4[1] + ws4[2] + ws4[3]) * (1.f / 16384.f);
}

// ---------------- SE MLP ----------------
__global__ void mlp_k(const float* __restrict__ w0, const float* __restrict__ A1,
                      const float* __restrict__ b1, const float* __restrict__ A2,
                      const float* __restrict__ b2, float* __restrict__ w0s) {
    int b = blockIdx.x, t = threadIdx.x;       // 128 threads
    __shared__ float w0r[64], hid[128];
    if (t < 64) w0r[t] = w0[b * 64 + t];
    __syncthreads();
    float s = b1[t];
    for (int c = 0; c < 64; ++c) s = fmaf(A1[t * 64 + c], w0r[c], s);
    hid[t] = fmaxf(s, 0.f);
    __syncthreads();
    if (t < 64) {
        float s2 = b2[t];
        for (int j = 0; j < 128; ++j) s2 = fmaf(A2[t * 128 + j], hid[j], s2);
        w0s[b * 64 + t] = 1.f / (1.f + expf(-s2));
    }
}

// ---------------- rgb gate: conv1x1 C->1 + bias ----------------
__global__ void rgb_k(const float* __restrict__ f2, const float* __restrict__ Rw,
                      const float* __restrict__ rb, float* __restrict__ rgb) {
    int by = blockIdx.x;
    int b = by >> 7, y = by & 127;
    int x = threadIdx.x;
    const float* p = f2 + (size_t)b * CHW + y * Wn + x;
    float s = rb[0];
    for (int c = 0; c < 64; ++c) s = fmaf(Rw[c], p[c * HW], s);
    rgb[by * Wn + x] = s;
}

// ---------------- f_b1 = f_blur * (1+w0s) * (1+rgb) ----------------
__global__ void fb1_k(const float4* __restrict__ fblur, const float* __restrict__ w0s,
                      const float4* __restrict__ rgb, float4* __restrict__ o) {
    int i = blockIdx.x * blockDim.x + threadIdx.x;
    int b = i >> 18;
    int c = (i >> 12) & 63;
    int pix4 = i & 4095;
    float s = 1.f + w0s[b * 64 + c];
    float4 f = fblur[i];
    float4 r = rgb[(b << 12) + pix4];
    o[i] = make_float4(f.x * s * (1.f + r.x), f.y * s * (1.f + r.y),
                       f.z * s * (1.f + r.z), f.w * s * (1.f + r.w));
}

// ---------------- dynamic per-pixel 3x3 conv (edge pad) + residual ----------------
__global__ __launch_bounds__(256) void dynconv_k(const float* __restrict__ fb,
                                                 const float* __restrict__ h,
                                                 const float* __restrict__ G2,
                                                 const float* __restrict__ g2b,
                                                 float* __restrict__ out) {
    __shared__ float tile[16 * 324];
    const int b  = blockIdx.z;
    const int by = blockIdx.y << 4, bx = blockIdx.x << 4;
    const int tid = threadIdx.x, tx = tid & 15, ty = tid >> 4;
    const int y = by + ty, x = bx + tx;

    float hr[64];
    const float* hp = h + (size_t)b * CHW + y * Wn + x;
#pragma unroll
    for (int ci = 0; ci < 64; ++ci) hr[ci] = hp[ci * HW];

    const float* fbb = fb + (size_t)b * CHW;
    for (int cc = 0; cc < 64; cc += 16) {
        __syncthreads();
        for (int idx = tid; idx < 16 * 324; idx += 256) {
            int ci = idx / 324;
            int p  = idx - ci * 324;
            int yy = p / 18, xx = p - yy * 18;
            int gy = min(max(by + yy - 1, 0), Hn - 1);
            int gx = min(max(bx + xx - 1, 0), Wn - 1);
            tile[idx] = fbb[(cc + ci) * HW + gy * Wn + gx];
        }
        __syncthreads();
#pragma unroll 1
        for (int c0 = 0; c0 < 16; ++c0) {
            const int c = cc + c0;
            float kv[9];
            const float* gb = g2b + c * 9;
#pragma unroll
            for (int t = 0; t < 9; ++t) kv[t] = gb[t];
            const float* g = G2 + (size_t)c * 9 * 64;
#pragma unroll
            for (int ci = 0; ci < 64; ++ci) {
                const float hv = hr[ci];
#pragma unroll
                for (int t = 0; t < 9; ++t) kv[t] = fmaf(g[t * 64 + ci], hv, kv[t]);
            }
            const int tb = c0 * 324 + ty * 18 + tx;
            float s = kv[0] * tile[tb]      + kv[1] * tile[tb + 1]  + kv[2] * tile[tb + 2]
                    + kv[3] * tile[tb + 18] + kv[4] * tile[tb + 19] + kv[5] * tile[tb + 20]
                    + kv[6] * tile[tb + 36] + kv[7] * tile[tb + 37] + kv[8] * tile[tb + 38];
            out[(size_t)b * CHW + c * HW + y * Wn + x] = tile[tb + 19] + s;
        }
    }
}

// ---------------- channel max/mean -> comp[B,2,H,W] ----------------
__global__ void comp_k(const float* __restrict__ sa, float* __restrict__ comp) {
    int by = blockIdx.x;
    int b = by >> 7, y = by & 127;
    int x = threadIdx.x;
    const float* p = sa + (size_t)b * CHW + y * Wn + x;
    float mx = p[0], sm = p[0];
    for (int c = 1; c < 64; ++c) { float v = p[c * HW]; mx = fmaxf(mx, v); sm += v; }
    float* cb = comp + (size_t)b * 2 * HW + y * Wn + x;
    cb[0]  = mx;
    cb[HW] = sm * (1.f / 64.f);
}

// ---------------- spatial 5x5 conv (2->1, pad 2, zero) + sigmoid ----------------
__global__ void sconv5_k(const float* __restrict__ comp, const float* __restrict__ Ew,
                         const float* __restrict__ eb, float* __restrict__ scale) {
    int id = blockIdx.x * 256 + threadIdx.x;
    int b = id >> 14, p = id & 16383;
    int y = p >> 7, x = p & 127;
    const float* cb = comp + (size_t)b * 2 * HW;
    float acc = eb[0];
#pragma unroll
    for (int ch = 0; ch < 2; ++ch)
#pragma unroll
        for (int ky = 0; ky < 5; ++ky) {
            int gy = y + ky - 2;
            if ((unsigned)gy >= (unsigned)Hn) continue;
#pragma unroll
            for (int kx = 0; kx < 5; ++kx) {
                int gx = x + kx - 2;
                if ((unsigned)gx >= (unsigned)Wn) continue;
                acc = fmaf(Ew[ch * 25 + ky * 5 + kx], cb[ch * HW + gy * Wn + gx], acc);
            }
        }
    scale[id] = 1.f / (1.f + expf(-acc));
}

// ---------------- final fusion: out = Fw @ concat(f_event*(1+scale), f_b2) ----------------
__global__ __launch_bounds__(256) void fuse_k(const float* __restrict__ fe,
                                              const float* __restrict__ scale,
                                              const float* __restrict__ fb2,
                                              const float* __restrict__ Fw,
                                              float* __restrict__ out) {
    __shared__ float tile[128 * 64];
    const int blk = blockIdx.x;
    const int b = blk >> 8;
    const int seg = blk & 255;
    const int pix0 = seg << 6;
    const int tid = threadIdx.x;
    const float* feb = fe  + (size_t)b * CHW + pix0;
    const float* fbb = fb2 + (size_t)b * CHW + pix0;
    const float* sc  = scale + b * HW + pix0;
    for (int idx = tid; idx < 8192; idx += 256) {
        int ci = idx >> 6, px = idx & 63;
        float v;
        if (ci < 64) v = feb[ci * HW + px] * (1.f + sc[px]);
        else         v = fbb[(ci - 64) * HW + px];
        tile[idx] = v;
    }
    __syncthreads();
    const int px = tid & 63, og = tid >> 6;
    float acc[32];
#pragma unroll
    for (int u = 0; u < 32; ++u) acc[u] = 0.f;
    const float* w = Fw + og * 32 * 128;
#pragma unroll 1
    for (int i = 0; i < 128; ++i) {
        float v = tile[i * 64 + px];
#pragma unroll
        for (int u = 0; u < 32; ++u) acc[u] = fmaf(w[u * 128 + i], v, acc[u]);
    }
    float* ob = out + (size_t)b * 2 * CHW + og * 32 * HW + pix0 + px;
#pragma unroll
    for (int u = 0; u < 32; ++u) ob[u * HW] = acc[u];
}

// ---------------- host launch ----------------
extern "C" void kernel_launch(void* const* d_in, const int* in_sizes, int n_in,
                              void* d_out, int out_size, void* d_ws, size_t ws_size,
                              hipStream_t stream) {
    const float* f_event = (const float*)d_in[0];
    const float* f_blur  = (const float*)d_in[1];
    const float* Wt1 = (const float*)d_in[2];
    const float* Wt2 = (const float*)d_in[3];
    const float* Wt3 = (const float*)d_in[4];
    const float* A1  = (const float*)d_in[5];
    const float* b1  = (const float*)d_in[6];
    const float* A2  = (const float*)d_in[7];
    const float* b2  = (const float*)d_in[8];
    const float* G1  = (const float*)d_in[9];
    const float* g1b = (const float*)d_in[10];
    const float* G2  = (const float*)d_in[11];
    const float* g2b = (const float*)d_in[12];
    const float* Rw  = (const float*)d_in[13];
    const float* rb  = (const float*)d_in[14];
    const float* S1  = (const float*)d_in[15];
    const float* S2  = (const float*)d_in[16];
    const float* Ew  = (const float*)d_in[17];
    const float* eb  = (const float*)d_in[18];
    const float* Fw  = (const float*)d_in[19];
    float* out = (float*)d_out;

    float* ws   = (float*)d_ws;
    float* bufA = ws;
    float* bufB = ws + (size_t)Bn * CHW;
    float* bufC = ws + (size_t)2 * Bn * CHW;
    float* w0    = ws + (size_t)3 * Bn * CHW;
    float* w0s   = w0 + 512;
    float* rgb   = w0s + 512;
    float* comp  = rgb + Bn * HW;
    float* scale = comp + 2 * Bn * HW;
    unsigned short* wprep = (unsigned short*)(scale + Bn * HW);  // 6 x 36864 bf16

    dim3 cgrid(Wn / 16, Hn / 16, Bn);          // 8x8x8
    const int n4 = Bn * CHW / 4;

    // 0. prep all conv weights into MFMA-friendly bf16 layout
    prep_w_k<<<dim3(144, 6), 256, 0, stream>>>(Wt1, Wt2, Wt3, G1, S1, S2, wprep);
    // 1. fused0 = f_event + f_blur
    add_k<<<n4 / 256, 256, 0, stream>>>((const float4*)f_event, (const float4*)f_blur,
                                        (float4*)bufA, n4);
    // 2. B = relu(conv(A, Wt1))
    conv3x3_mfma<true, false, false><<<cgrid, 256, 0, stream>>>(bufA, wprep + 0 * 36864, nullptr, bufB);
    // 3. A = conv(B, Wt2)  -> "fused"
    conv3x3_mfma<false, false, false><<<cgrid, 256, 0, stream>>>(bufB, wprep + 1 * 36864, nullptr, bufA);
    // 4. SE gate
    mean_hw_k<<<Bn * Cn, 256, 0, stream>>>(bufA, w0);
    mlp_k<<<Bn, 128, 0, stream>>>(w0, A1, b1, A2, b2, w0s);
    // 5. B = A + relu(conv(A, Wt3)) -> fused2
    conv3x3_mfma<true, false, true><<<cgrid, 256, 0, stream>>>(bufA, wprep + 2 * 36864, nullptr, bufB);
    // 6. rgb gate from fused2
    rgb_k<<<Bn * Hn, Wn, 0, stream>>>(bufB, Rw, rb, rgb);
    // 7. C = f_blur * (1+w0s) * (1+rgb)  -> f_b1
    fb1_k<<<n4 / 256, 256, 0, stream>>>((const float4*)f_blur, w0s,
                                        (const float4*)rgb, (float4*)bufC);
    // 8. A = relu(conv(f_event, G1) + g1b)  -> h
    conv3x3_mfma<true, true, false><<<cgrid, 256, 0, stream>>>(f_event, wprep + 3 * 36864, g1b, bufA);
    // 9. B = C + dynconv(C, kern(A))  -> f_b2
    dynconv_k<<<cgrid, 256, 0, stream>>>(bufC, bufA, G2, g2b, bufB);
    // 10. sa = conv(relu(conv(f_event,S1)), S2)
    conv3x3_mfma<true, false, false><<<cgrid, 256, 0, stream>>>(f_event, wprep + 4 * 36864, nullptr, bufA);
    conv3x3_mfma<false, false, false><<<cgrid, 256, 0, stream>>>(bufA, wprep + 5 * 36864, nullptr, bufC);
    // 11. comp + 5x5 conv + sigmoid -> scale_e
    comp_k<<<Bn * Hn, Wn, 0, stream>>>(bufC, comp);
    sconv5_k<<<Bn * HW / 256, 256, 0, stream>>>(comp, Ew, eb, scale);
    // 12. out = Fw @ concat(f_event*(1+scale_e), f_b2)
    fuse_k<<<Bn * HW / 64, 256, 0, stream>>>(f_event, scale, bufB, Fw, out);
}

// Round 4
// 832.206 us; speedup vs baseline: 3.7885x; 1.1743x over previous
//
#include <hip/hip_runtime.h>
#include <math.h>

constexpr int Bn = 8, Cn = 64, Hn = 128, Wn = 128;
constexpr int HW  = Hn * Wn;      // 16384
constexpr int CHW = Cn * HW;      // 1048576

typedef float  f32x4  __attribute__((ext_vector_type(4)));
typedef __bf16 bf16x8 __attribute__((ext_vector_type(8)));
typedef unsigned int u32x4 __attribute__((ext_vector_type(4)));

static __device__ __forceinline__ unsigned short f2bf(float f) {
    unsigned u = __builtin_bit_cast(unsigned, f);
    u = (u + 0x7FFF + ((u >> 16) & 1)) >> 16;
    return (unsigned short)u;
}
static __device__ __forceinline__ float bf2f(unsigned short v) {
    unsigned u = (unsigned)v << 16;
    return __builtin_bit_cast(float, u);
}

// ---------------- elementwise add: A = f_event + f_blur ----------------
__global__ void add_k(const float4* __restrict__ a, const float4* __restrict__ b,
                      float4* __restrict__ o, int n4) {
    int i = blockIdx.x * blockDim.x + threadIdx.x;
    if (i < n4) {
        float4 x = a[i], y = b[i];
        o[i] = make_float4(x.x + y.x, x.y + y.y, x.z + y.z, x.w + y.w);
    }
}

// ---------------- weight prep: OIHW fp32 -> [h][s][t][co][8cj] bf16 ----------------
__global__ void prep_w_k(const float* __restrict__ W0, const float* __restrict__ W1,
                         const float* __restrict__ W2, const float* __restrict__ W3,
                         const float* __restrict__ W4, const float* __restrict__ W5,
                         unsigned short* __restrict__ dst) {
    int i = blockIdx.x * 256 + threadIdx.x;
    if (i >= 36864) return;
    const float* W = W0;
    switch (blockIdx.y) {
        case 1: W = W1; break; case 2: W = W2; break;
        case 3: W = W3; break; case 4: W = W4; break; case 5: W = W5; break;
        default: break;
    }
    int cj = i & 7;
    int rest = i >> 3;
    int co = rest & 63;
    rest >>= 6;              // (h*4+s)*9 + t
    int t  = rest % 9;
    int hs = rest / 9;       // 0..7
    int ci = hs * 8 + cj;
    dst[(size_t)blockIdx.y * 36864 + i] = f2bf(W[(co * 64 + ci) * 9 + t]);
}

// ---------------- conv3x3 via MFMA, C=64->64, zero pad=1 ----------------
template<bool RELU, bool BIAS, bool ADD_INPUT>
__global__ __launch_bounds__(256, 2) void conv3x3_mfma(
        const float* __restrict__ in, const unsigned short* __restrict__ Wp,
        const float* __restrict__ bias, float* __restrict__ out) {
    __shared__ unsigned short smIn[10368];   // 4 x 324 x 8 = 20.25 KB
    __shared__ unsigned short smW[18432];    // 4 x 9 x 64 x 8 = 36 KB
    const int b  = blockIdx.z;
    const int by = blockIdx.y << 4, bx = blockIdx.x << 4;
    const int tid = threadIdx.x;
    const int lane = tid & 63, w = tid >> 6;
    const int lx = lane & 15, ls = lane >> 4;
    const float* inb = in + (size_t)b * CHW;

    f32x4 acc[4][4];
#pragma unroll
    for (int m = 0; m < 4; ++m)
#pragma unroll
        for (int n = 0; n < 4; ++n) acc[m][n] = f32x4{0.f, 0.f, 0.f, 0.f};

    for (int h = 0; h < 2; ++h) {
        __syncthreads();
        {
            const int cibase = h << 5;
            for (int idx = tid; idx < 5184; idx += 256) {
                int c2 = idx / 324;
                int p  = idx - c2 * 324;
                int yy = p / 18, xx = p - yy * 18;
                int gy = by + yy - 1, gx = bx + xx - 1;
                unsigned pk = 0;
                if ((unsigned)gy < (unsigned)Hn && (unsigned)gx < (unsigned)Wn) {
                    const float* sp = inb + (size_t)(cibase + c2 * 2) * HW + gy * Wn + gx;
                    pk = (unsigned)f2bf(sp[0]) | ((unsigned)f2bf(sp[HW]) << 16);
                }
                ((unsigned*)smIn)[(c2 >> 2) * 1296 + p * 4 + (c2 & 3)] = pk;
            }
        }
        {
            const u32x4* src = (const u32x4*)(Wp + h * 18432);
            u32x4* dst = (u32x4*)smW;
            for (int i = tid; i < 2304; i += 256) dst[i] = src[i];
        }
        __syncthreads();

#pragma unroll
        for (int ky = 0; ky < 3; ++ky)
#pragma unroll
        for (int kx = 0; kx < 3; ++kx) {
            const int t = ky * 3 + kx;
            bf16x8 a[4];
            const unsigned short* wbase = smW + ls * 4608 + t * 512 + lx * 8;
#pragma unroll
            for (int m = 0; m < 4; ++m)
                a[m] = *(const bf16x8*)(wbase + m * 128);
            const unsigned short* ibase =
                smIn + ls * 2592 + (((4 * w + ky) * 18) + lx + kx) * 8;
#pragma unroll
            for (int n = 0; n < 4; ++n) {
                bf16x8 bf = *(const bf16x8*)(ibase + n * 144);
#pragma unroll
                for (int m = 0; m < 4; ++m)
                    acc[m][n] = __builtin_amdgcn_mfma_f32_16x16x32_bf16(
                        a[m], bf, acc[m][n], 0, 0, 0);
            }
        }
    }

    const int y0 = by + 4 * w;
    const size_t outb = (size_t)b * CHW;
#pragma unroll
    for (int m = 0; m < 4; ++m) {
#pragma unroll
        for (int r = 0; r < 4; ++r) {
            const int co = 16 * m + ls * 4 + r;
            float bv = 0.f;
            if constexpr (BIAS) bv = bias[co];
#pragma unroll
            for (int n = 0; n < 4; ++n) {
                float v = acc[m][n][r] + bv;
                if constexpr (RELU) v = fmaxf(v, 0.f);
                const size_t off = outb + (size_t)co * HW + (size_t)(y0 + n) * Wn + bx + lx;
                if constexpr (ADD_INPUT) v += in[off];
                out[off] = v;
            }
        }
    }
}

// ---------------- pass 1: kern = g2b + G2 @ h  (1x1 conv 64->576, bf16 out) ----
// One batch per launch. Block = 128-px linear tile, 4 waves.
// Wave w: rows (chunk*64 + (w&1)*32 + [0,32)) x px ((w>>1)*64 + [0,64)).
__global__ __launch_bounds__(256, 2) void kerngen_k(
        const float* __restrict__ h, const float* __restrict__ G2,
        const float* __restrict__ g2b, unsigned short* __restrict__ kern, int b) {
    __shared__ unsigned short smH[8192];   // [oct8][px128][8ci] 16 KB
    __shared__ unsigned short smG[4096];   // [oct8][row64][8ci]  8 KB
    __shared__ unsigned short smK[8192];   // [wave4][row32][px64] 16 KB
    const int tile = blockIdx.x;           // 0..127
    const int tid = threadIdx.x;
    const int lane = tid & 63, w = tid >> 6;
    const int lx = lane & 15, ls = lane >> 4;
    const int wr = w & 1, wc = w >> 1;

    // stage h tile: 64 ci x 128 px -> bf16 planes
    {
        const float* hb = h + (size_t)b * CHW + tile * 128;
#pragma unroll
        for (int it = 0; it < 4; ++it) {
            int i = tid + it * 256;        // 0..1023
            int px = i & 127, oct = i >> 7;
            const float* sp = hb + (size_t)oct * 8 * HW + px;
            unsigned short v[8];
#pragma unroll
            for (int j = 0; j < 8; ++j) v[j] = f2bf(sp[(size_t)j * HW]);
            u32x4 pk;
            pk[0] = (unsigned)v[0] | ((unsigned)v[1] << 16);
            pk[1] = (unsigned)v[2] | ((unsigned)v[3] << 16);
            pk[2] = (unsigned)v[4] | ((unsigned)v[5] << 16);
            pk[3] = (unsigned)v[6] | ((unsigned)v[7] << 16);
            ((u32x4*)smH)[oct * 128 + px] = pk;
        }
    }

    for (int chunk = 0; chunk < 9; ++chunk) {
        __syncthreads();                   // smG safe to overwrite (+ smH ready)
        // stage G2 rows [chunk*64, +64): 512 x b128 writes
#pragma unroll
        for (int it = 0; it < 2; ++it) {
            int i = tid + it * 256;        // 0..511
            int oct = i & 7, row = i >> 3;
            const float* gp = G2 + (size_t)(chunk * 64 + row) * 64 + oct * 8;
            float4 g0 = *(const float4*)gp;
            float4 g1 = *(const float4*)(gp + 4);
            u32x4 pk;
            pk[0] = (unsigned)f2bf(g0.x) | ((unsigned)f2bf(g0.y) << 16);
            pk[1] = (unsigned)f2bf(g0.z) | ((unsigned)f2bf(g0.w) << 16);
            pk[2] = (unsigned)f2bf(g1.x) | ((unsigned)f2bf(g1.y) << 16);
            pk[3] = (unsigned)f2bf(g1.z) | ((unsigned)f2bf(g1.w) << 16);
            ((u32x4*)smG)[oct * 64 + row] = pk;
        }
        __syncthreads();

        f32x4 acc[2][4];
#pragma unroll
        for (int m = 0; m < 2; ++m)
#pragma unroll
            for (int n = 0; n < 4; ++n) acc[m][n] = f32x4{0.f, 0.f, 0.f, 0.f};

#pragma unroll
        for (int k = 0; k < 2; ++k) {
            bf16x8 a[2];
#pragma unroll
            for (int m = 0; m < 2; ++m)
                a[m] = *(const bf16x8*)(smG + ((k * 4 + ls) * 64 + wr * 32 + 16 * m + lx) * 8);
#pragma unroll
            for (int n = 0; n < 4; ++n) {
                bf16x8 bv = *(const bf16x8*)(smH + ((k * 4 + ls) * 128 + wc * 64 + 16 * n + lx) * 8);
#pragma unroll
                for (int m = 0; m < 2; ++m)
                    acc[m][n] = __builtin_amdgcn_mfma_f32_16x16x32_bf16(
                        a[m], bv, acc[m][n], 0, 0, 0);
            }
        }

        // bias + write own smK region (rows local 0..31 = 16m+ls*4+r, px 16n+lx)
#pragma unroll
        for (int m = 0; m < 2; ++m) {
            const float4 bias = *(const float4*)(g2b + chunk * 64 + wr * 32 + m * 16 + ls * 4);
            const float bb[4] = {bias.x, bias.y, bias.z, bias.w};
#pragma unroll
            for (int n = 0; n < 4; ++n)
#pragma unroll
                for (int r = 0; r < 4; ++r)
                    smK[w * 2048 + (16 * m + ls * 4 + r) * 64 + 16 * n + lx] =
                        f2bf(acc[m][n][r] + bb[r]);
        }
        // copy own region to global: rows of 64 px = 128 B contiguous
        const int row8 = lane >> 3, sub = lane & 7;
#pragma unroll
        for (int it = 0; it < 4; ++it) {
            int row = it * 8 + row8;
            u32x4 d = ((const u32x4*)smK)[w * 256 + row * 8 + sub];
            int rowg = chunk * 64 + wr * 32 + row;
            int pxg  = tile * 128 + wc * 64 + sub * 8;
            *(u32x4*)(kern + (size_t)rowg * HW + pxg) = d;
        }
    }
}

// ---------------- pass 2: out = fb + sum_t kern[c*9+t] * patch (edge pad) ------
// One batch per launch; blockIdx.z = channel quarter.
__global__ __launch_bounds__(256) void apply_k(
        const float* __restrict__ fb, const unsigned short* __restrict__ kern,
        float* __restrict__ out, int b) {
    __shared__ float tile[16 * 324];
    const int cq = blockIdx.z;
    const int by = blockIdx.y << 4, bx = blockIdx.x << 4;
    const int tid = threadIdx.x, tx = tid & 15, ty = tid >> 4;
    const int y = by + ty, x = bx + tx;
    const float* fbb = fb + (size_t)b * CHW;

    for (int idx = tid; idx < 16 * 324; idx += 256) {
        int ci = idx / 324;
        int p  = idx - ci * 324;
        int yy = p / 18, xx = p - yy * 18;
        int gy = min(max(by + yy - 1, 0), Hn - 1);
        int gx = min(max(bx + xx - 1, 0), Wn - 1);
        tile[idx] = fbb[(size_t)(cq * 16 + ci) * HW + gy * Wn + gx];
    }
    __syncthreads();

    const int pxg = y * Wn + x;
#pragma unroll 1
    for (int c0 = 0; c0 < 16; ++c0) {
        const int c = cq * 16 + c0;
        const unsigned short* kp = kern + (size_t)(c * 9) * HW + pxg;
        const int tb = c0 * 324 + ty * 18 + tx;
        float s = 0.f;
#pragma unroll
        for (int t = 0; t < 9; ++t)
            s = fmaf(bf2f(kp[(size_t)t * HW]), tile[tb + (t / 3) * 18 + (t % 3)], s);
        out[(size_t)b * CHW + (size_t)c * HW + pxg] = tile[tb + 19] + s;
    }
}

// ---------------- mean over H,W per (b,c) ----------------
__global__ void mean_hw_k(const float* __restrict__ in, float* __restrict__ w0) {
    int bc = blockIdx.x;
    const float* p = in + (size_t)bc * HW;
    float s = 0.f;
    for (int i = threadIdx.x; i < HW; i += 256) s += p[i];
#pragma unroll
    for (int off = 32; off; off >>= 1) s += __shfl_down(s, off);
    __shared__ float ws4[4];
    if ((threadIdx.x & 63) == 0) ws4[threadIdx.x >> 6] = s;
    __syncthreads();
    if (threadIdx.x == 0)
        w0[bc] = (ws4[0] + ws4[1] + ws4[2] + ws4[3]) * (1.f / 16384.f);
}

// ---------------- SE MLP ----------------
__global__ void mlp_k(const float* __restrict__ w0, const float* __restrict__ A1,
                      const float* __restrict__ b1, const float* __restrict__ A2,
                      const float* __restrict__ b2, float* __restrict__ w0s) {
    int b = blockIdx.x, t = threadIdx.x;       // 128 threads
    __shared__ float w0r[64], hid[128];
    if (t < 64) w0r[t] = w0[b * 64 + t];
    __syncthreads();
    float s = b1[t];
    for (int c = 0; c < 64; ++c) s = fmaf(A1[t * 64 + c], w0r[c], s);
    hid[t] = fmaxf(s, 0.f);
    __syncthreads();
    if (t < 64) {
        float s2 = b2[t];
        for (int j = 0; j < 128; ++j) s2 = fmaf(A2[t * 128 + j], hid[j], s2);
        w0s[b * 64 + t] = 1.f / (1.f + expf(-s2));
    }
}

// ---------------- rgb gate: conv1x1 C->1 + bias ----------------
__global__ void rgb_k(const float* __restrict__ f2, const float* __restrict__ Rw,
                      const float* __restrict__ rb, float* __restrict__ rgb) {
    int by = blockIdx.x;
    int b = by >> 7, y = by & 127;
    int x = threadIdx.x;
    const float* p = f2 + (size_t)b * CHW + y * Wn + x;
    float s = rb[0];
    for (int c = 0; c < 64; ++c) s = fmaf(Rw[c], p[c * HW], s);
    rgb[by * Wn + x] = s;
}

// ---------------- f_b1 = f_blur * (1+w0s) * (1+rgb) ----------------
__global__ void fb1_k(const float4* __restrict__ fblur, const float* __restrict__ w0s,
                      const float4* __restrict__ rgb, float4* __restrict__ o) {
    int i = blockIdx.x * blockDim.x + threadIdx.x;
    int b = i >> 18;
    int c = (i >> 12) & 63;
    int pix4 = i & 4095;
    float s = 1.f + w0s[b * 64 + c];
    float4 f = fblur[i];
    float4 r = rgb[(b << 12) + pix4];
    o[i] = make_float4(f.x * s * (1.f + r.x), f.y * s * (1.f + r.y),
                       f.z * s * (1.f + r.z), f.w * s * (1.f + r.w));
}

// ---------------- channel max/mean -> comp[B,2,H,W] ----------------
__global__ void comp_k(const float* __restrict__ sa, float* __restrict__ comp) {
    int by = blockIdx.x;
    int b = by >> 7, y = by & 127;
    int x = threadIdx.x;
    const float* p = sa + (size_t)b * CHW + y * Wn + x;
    float mx = p[0], sm = p[0];
    for (int c = 1; c < 64; ++c) { float v = p[c * HW]; mx = fmaxf(mx, v); sm += v; }
    float* cb = comp + (size_t)b * 2 * HW + y * Wn + x;
    cb[0]  = mx;
    cb[HW] = sm * (1.f / 64.f);
}

// ---------------- spatial 5x5 conv (2->1, pad 2, zero) + sigmoid ----------------
__global__ void sconv5_k(const float* __restrict__ comp, const float* __restrict__ Ew,
                         const float* __restrict__ eb, float* __restrict__ scale) {
    int id = blockIdx.x * 256 + threadIdx.x;
    int b = id >> 14, p = id & 16383;
    int y = p >> 7, x = p & 127;
    const float* cb = comp + (size_t)b * 2 * HW;
    float acc = eb[0];
#pragma unroll
    for (int ch = 0; ch < 2; ++ch)
#pragma unroll
        for (int ky = 0; ky < 5; ++ky) {
            int gy = y + ky - 2;
            if ((unsigned)gy >= (unsigned)Hn) continue;
#pragma unroll
            for (int kx = 0; kx < 5; ++kx) {
                int gx = x + kx - 2;
                if ((unsigned)gx >= (unsigned)Wn) continue;
                acc = fmaf(Ew[ch * 25 + ky * 5 + kx], cb[ch * HW + gy * Wn + gx], acc);
            }
        }
    scale[id] = 1.f / (1.f + expf(-acc));
}

// ---------------- final fusion: out = Fw @ concat(f_event*(1+scale), f_b2) ----
__global__ __launch_bounds__(256) void fuse_k(const float* __restrict__ fe,
                                              const float* __restrict__ scale,
                                              const float* __restrict__ fb2,
                                              const float* __restrict__ Fw,
                                              float* __restrict__ out) {
    __shared__ float tile[128 * 64];
    const int blk = blockIdx.x;
    const int b = blk >> 8;
    const int seg = blk & 255;
    const int pix0 = seg << 6;
    const int tid = threadIdx.x;
    const float* feb = fe  + (size_t)b * CHW + pix0;
    const float* fbb = fb2 + (size_t)b * CHW + pix0;
    const float* sc  = scale + b * HW + pix0;
    for (int idx = tid; idx < 8192; idx += 256) {
        int ci = idx >> 6, px = idx & 63;
        float v;
        if (ci < 64) v = feb[ci * HW + px] * (1.f + sc[px]);
        else         v = fbb[(ci - 64) * HW + px];
        tile[idx] = v;
    }
    __syncthreads();
    const int px = tid & 63, og = tid >> 6;
    float acc[32];
#pragma unroll
    for (int u = 0; u < 32; ++u) acc[u] = 0.f;
    const float* w = Fw + og * 32 * 128;
#pragma unroll 1
    for (int i = 0; i < 128; ++i) {
        float v = tile[i * 64 + px];
#pragma unroll
        for (int u = 0; u < 32; ++u) acc[u] = fmaf(w[u * 128 + i], v, acc[u]);
    }
    float* ob = out + (size_t)b * 2 * CHW + og * 32 * HW + pix0 + px;
#pragma unroll
    for (int u = 0; u < 32; ++u) ob[u * HW] = acc[u];
}

// ---------------- host launch ----------------
extern "C" void kernel_launch(void* const* d_in, const int* in_sizes, int n_in,
                              void* d_out, int out_size, void* d_ws, size_t ws_size,
                              hipStream_t stream) {
    const float* f_event = (const float*)d_in[0];
    const float* f_blur  = (const float*)d_in[1];
    const float* Wt1 = (const float*)d_in[2];
    const float* Wt2 = (const float*)d_in[3];
    const float* Wt3 = (const float*)d_in[4];
    const float* A1  = (const float*)d_in[5];
    const float* b1  = (const float*)d_in[6];
    const float* A2  = (const float*)d_in[7];
    const float* b2  = (const float*)d_in[8];
    const float* G1  = (const float*)d_in[9];
    const float* g1b = (const float*)d_in[10];
    const float* G2  = (const float*)d_in[11];
    const float* g2b = (const float*)d_in[12];
    const float* Rw  = (const float*)d_in[13];
    const float* rb  = (const float*)d_in[14];
    const float* S1  = (const float*)d_in[15];
    const float* S2  = (const float*)d_in[16];
    const float* Ew  = (const float*)d_in[17];
    const float* eb  = (const float*)d_in[18];
    const float* Fw  = (const float*)d_in[19];
    float* out = (float*)d_out;

    float* ws   = (float*)d_ws;
    float* bufA = ws;
    float* bufB = ws + (size_t)Bn * CHW;
    float* bufC = ws + (size_t)2 * Bn * CHW;
    float* w0    = ws + (size_t)3 * Bn * CHW;
    float* w0s   = w0 + 512;
    float* rgb   = w0s + 512;
    float* comp  = rgb + Bn * HW;
    float* scale = comp + 2 * Bn * HW;
    unsigned short* wprep = (unsigned short*)(scale + Bn * HW);  // 6 x 36864 bf16
    unsigned short* kernbuf = wprep + 6 * 36864;                 // 576*HW bf16 (18.9 MB)

    dim3 cgrid(Wn / 16, Hn / 16, Bn);          // 8x8x8
    const int n4 = Bn * CHW / 4;

    // 0. prep all conv weights into MFMA-friendly bf16 layout
    prep_w_k<<<dim3(144, 6), 256, 0, stream>>>(Wt1, Wt2, Wt3, G1, S1, S2, wprep);
    // 1. fused0 = f_event + f_blur
    add_k<<<n4 / 256, 256, 0, stream>>>((const float4*)f_event, (const float4*)f_blur,
                                        (float4*)bufA, n4);
    // 2. B = relu(conv(A, Wt1))
    conv3x3_mfma<true, false, false><<<cgrid, 256, 0, stream>>>(bufA, wprep + 0 * 36864, nullptr, bufB);
    // 3. A = conv(B, Wt2)  -> "fused"
    conv3x3_mfma<false, false, false><<<cgrid, 256, 0, stream>>>(bufB, wprep + 1 * 36864, nullptr, bufA);
    // 4. SE gate
    mean_hw_k<<<Bn * Cn, 256, 0, stream>>>(bufA, w0);
    mlp_k<<<Bn, 128, 0, stream>>>(w0, A1, b1, A2, b2, w0s);
    // 5. B = A + relu(conv(A, Wt3)) -> fused2
    conv3x3_mfma<true, false, true><<<cgrid, 256, 0, stream>>>(bufA, wprep + 2 * 36864, nullptr, bufB);
    // 6. rgb gate from fused2
    rgb_k<<<Bn * Hn, Wn, 0, stream>>>(bufB, Rw, rb, rgb);
    // 7. C = f_blur * (1+w0s) * (1+rgb)  -> f_b1
    fb1_k<<<n4 / 256, 256, 0, stream>>>((const float4*)f_blur, w0s,
                                        (const float4*)rgb, (float4*)bufC);
    // 8. A = relu(conv(f_event, G1) + g1b)  -> h
    conv3x3_mfma<true, true, false><<<cgrid, 256, 0, stream>>>(f_event, wprep + 3 * 36864, g1b, bufA);
    // 9. per batch: kern = G2@h + g2b (MFMA GEMM, bf16), then apply dynconv
    for (int b = 0; b < Bn; ++b) {
        kerngen_k<<<dim3(128), 256, 0, stream>>>(bufA, G2, g2b, kernbuf, b);
        apply_k<<<dim3(8, 8, 4), 256, 0, stream>>>(bufC, kernbuf, bufB, b);
    }
    // 10. sa = conv(relu(conv(f_event,S1)), S2)
    conv3x3_mfma<true, false, false><<<cgrid, 256, 0, stream>>>(f_event, wprep + 4 * 36864, nullptr, bufA);
    conv3x3_mfma<false, false, false><<<cgrid, 256, 0, stream>>>(bufA, wprep + 5 * 36864, nullptr, bufC);
    // 11. comp + 5x5 conv + sigmoid -> scale_e
    comp_k<<<Bn * Hn, Wn, 0, stream>>>(bufC, comp);
    sconv5_k<<<Bn * HW / 256, 256, 0, stream>>>(comp, Ew, eb, scale);
    // 12. out = Fw @ concat(f_event*(1+scale_e), f_b2)
    fuse_k<<<Bn * HW / 64, 256, 0, stream>>>(f_event, scale, bufB, Fw, out);
}

// Round 5
// 401.851 us; speedup vs baseline: 7.8458x; 2.0709x over previous
//
#include <hip/hip_runtime.h>
#include <math.h>

constexpr int Bn = 8, Cn = 64, Hn = 128, Wn = 128;
constexpr int HW  = Hn * Wn;      // 16384
constexpr int CHW = Cn * HW;      // 1048576

typedef float  f32x4  __attribute__((ext_vector_type(4)));
typedef __bf16 bf16x8 __attribute__((ext_vector_type(8)));
typedef unsigned int u32x4 __attribute__((ext_vector_type(4)));

static __device__ __forceinline__ unsigned short f2bf(float f) {
    unsigned u = __builtin_bit_cast(unsigned, f);
    u = (u + 0x7FFF + ((u >> 16) & 1)) >> 16;
    return (unsigned short)u;
}
static __device__ __forceinline__ float bf2f(unsigned short v) {
    unsigned u = (unsigned)v << 16;
    return __builtin_bit_cast(float, u);
}

// ---------------- elementwise add: A = f_event + f_blur ----------------
__global__ void add_k(const float4* __restrict__ a, const float4* __restrict__ b,
                      float4* __restrict__ o, int n4) {
    int i = blockIdx.x * blockDim.x + threadIdx.x;
    if (i < n4) {
        float4 x = a[i], y = b[i];
        o[i] = make_float4(x.x + y.x, x.y + y.y, x.z + y.z, x.w + y.w);
    }
}

// ---------------- weight prep: OIHW fp32 -> [h][s][t][co][8cj] bf16 ----------------
__global__ void prep_w_k(const float* __restrict__ W0, const float* __restrict__ W1,
                         const float* __restrict__ W2, const float* __restrict__ W3,
                         const float* __restrict__ W4, const float* __restrict__ W5,
                         unsigned short* __restrict__ dst) {
    int i = blockIdx.x * 256 + threadIdx.x;
    if (i >= 36864) return;
    const float* W = W0;
    switch (blockIdx.y) {
        case 1: W = W1; break; case 2: W = W2; break;
        case 3: W = W3; break; case 4: W = W4; break; case 5: W = W5; break;
        default: break;
    }
    int cj = i & 7;
    int rest = i >> 3;
    int co = rest & 63;
    rest >>= 6;              // (h*4+s)*9 + t
    int t  = rest % 9;
    int hs = rest / 9;       // 0..7
    int ci = hs * 8 + cj;
    dst[(size_t)blockIdx.y * 36864 + i] = f2bf(W[(co * 64 + ci) * 9 + t]);
}

// ---------------- prep2: G2 [576x64] and Fw [128x128] -> bf16 row-major --------
__global__ void prep2_k(const float* __restrict__ G2, const float* __restrict__ Fw,
                        unsigned short* __restrict__ G2p, unsigned short* __restrict__ Fwp) {
    int i = blockIdx.x * 256 + threadIdx.x;
    if (i < 36864) G2p[i] = f2bf(G2[i]);
    else if (i < 36864 + 16384) Fwp[i - 36864] = f2bf(Fw[i - 36864]);
}

// ---------------- conv3x3 via MFMA, C=64->64, zero pad=1 ----------------
template<bool RELU, bool BIAS, bool ADD_INPUT>
__global__ __launch_bounds__(256, 2) void conv3x3_mfma(
        const float* __restrict__ in, const unsigned short* __restrict__ Wp,
        const float* __restrict__ bias, float* __restrict__ out) {
    __shared__ unsigned short smIn[10368];   // 4 x 324 x 8 = 20.25 KB
    __shared__ unsigned short smW[18432];    // 4 x 9 x 64 x 8 = 36 KB
    const int b  = blockIdx.z;
    const int by = blockIdx.y << 4, bx = blockIdx.x << 4;
    const int tid = threadIdx.x;
    const int lane = tid & 63, w = tid >> 6;
    const int lx = lane & 15, ls = lane >> 4;
    const float* inb = in + (size_t)b * CHW;

    f32x4 acc[4][4];
#pragma unroll
    for (int m = 0; m < 4; ++m)
#pragma unroll
        for (int n = 0; n < 4; ++n) acc[m][n] = f32x4{0.f, 0.f, 0.f, 0.f};

    for (int h = 0; h < 2; ++h) {
        __syncthreads();
        {
            const int cibase = h << 5;
            for (int idx = tid; idx < 5184; idx += 256) {
                int c2 = idx / 324;
                int p  = idx - c2 * 324;
                int yy = p / 18, xx = p - yy * 18;
                int gy = by + yy - 1, gx = bx + xx - 1;
                unsigned pk = 0;
                if ((unsigned)gy < (unsigned)Hn && (unsigned)gx < (unsigned)Wn) {
                    const float* sp = inb + (size_t)(cibase + c2 * 2) * HW + gy * Wn + gx;
                    pk = (unsigned)f2bf(sp[0]) | ((unsigned)f2bf(sp[HW]) << 16);
                }
                ((unsigned*)smIn)[(c2 >> 2) * 1296 + p * 4 + (c2 & 3)] = pk;
            }
        }
        {
            const u32x4* src = (const u32x4*)(Wp + h * 18432);
            u32x4* dst = (u32x4*)smW;
            for (int i = tid; i < 2304; i += 256) dst[i] = src[i];
        }
        __syncthreads();

#pragma unroll
        for (int ky = 0; ky < 3; ++ky)
#pragma unroll
        for (int kx = 0; kx < 3; ++kx) {
            const int t = ky * 3 + kx;
            bf16x8 a[4];
            const unsigned short* wbase = smW + ls * 4608 + t * 512 + lx * 8;
#pragma unroll
            for (int m = 0; m < 4; ++m)
                a[m] = *(const bf16x8*)(wbase + m * 128);
            const unsigned short* ibase =
                smIn + ls * 2592 + (((4 * w + ky) * 18) + lx + kx) * 8;
#pragma unroll
            for (int n = 0; n < 4; ++n) {
                bf16x8 bf = *(const bf16x8*)(ibase + n * 144);
#pragma unroll
                for (int m = 0; m < 4; ++m)
                    acc[m][n] = __builtin_amdgcn_mfma_f32_16x16x32_bf16(
                        a[m], bf, acc[m][n], 0, 0, 0);
            }
        }
    }

    const int y0 = by + 4 * w;
    const size_t outb = (size_t)b * CHW;
#pragma unroll
    for (int m = 0; m < 4; ++m) {
#pragma unroll
        for (int r = 0; r < 4; ++r) {
            const int co = 16 * m + ls * 4 + r;
            float bv = 0.f;
            if constexpr (BIAS) bv = bias[co];
#pragma unroll
            for (int n = 0; n < 4; ++n) {
                float v = acc[m][n][r] + bv;
                if constexpr (RELU) v = fmaxf(v, 0.f);
                const size_t off = outb + (size_t)co * HW + (size_t)(y0 + n) * Wn + bx + lx;
                if constexpr (ADD_INPUT) v += in[off];
                out[off] = v;
            }
        }
    }
}

// ---------------- fused dynamic conv: kern GEMM + per-pixel apply --------------
// Block: 16x8 px tile (128 px), 4 waves. Thread = 1 px x channel-parity half.
// Per chunk (64 kern rows): GEMM (a-frags from global G2p, b-frags from smH),
// epilogue -> XOR-swizzled smK (double-buffered), barrier, unrolled apply.
__global__ __launch_bounds__(256, 2) void dynfused_k(
        const float* __restrict__ fb, const float* __restrict__ h,
        const unsigned short* __restrict__ G2p, const float* __restrict__ g2b,
        float* __restrict__ out) {
    __shared__ unsigned short smH[8192];       // [oct8][px128][8ci] 16 KB
    __shared__ unsigned short smFB[11520];     // [c64][p180] 22.5 KB (10x18 patch)
    __shared__ unsigned short smK[2][8192];    // dbuf [r64][px128 swz] 2x16 KB
    const int b  = blockIdx.z;
    const int by = blockIdx.y << 3, bx = blockIdx.x << 4;
    const int tid = threadIdx.x;
    const int lane = tid & 63, w = tid >> 6;
    const int lx = lane & 15, ls = lane >> 4;
    const int wr = w & 1, wc = w >> 1;
    const int px = tid & 127;
    const int chalf = __builtin_amdgcn_readfirstlane(tid >> 7);  // wave-uniform
    const int ty = px >> 4, tx = px & 15;

    const float* fbb = fb + (size_t)b * CHW;
    const float* hb  = h  + (size_t)b * CHW;

    // stage h: 64ci x 128px -> [oct][px][8]
#pragma unroll
    for (int it = 0; it < 4; ++it) {
        int i = tid + it * 256;
        int p = i & 127, oct = i >> 7;
        const float* sp = hb + (size_t)oct * 8 * HW + (by + (p >> 4)) * Wn + bx + (p & 15);
        unsigned short v[8];
#pragma unroll
        for (int j = 0; j < 8; ++j) v[j] = f2bf(sp[(size_t)j * HW]);
        u32x4 pk;
        pk[0] = (unsigned)v[0] | ((unsigned)v[1] << 16);
        pk[1] = (unsigned)v[2] | ((unsigned)v[3] << 16);
        pk[2] = (unsigned)v[4] | ((unsigned)v[5] << 16);
        pk[3] = (unsigned)v[6] | ((unsigned)v[7] << 16);
        ((u32x4*)smH)[oct * 128 + p] = pk;
    }
    // stage fb patch: 64ch x 10x18, edge-clamped
    for (int i = tid; i < 11520; i += 256) {
        int c = i / 180, p = i - c * 180;
        int pr = p / 18, pc = p - pr * 18;
        int gy = min(max(by + pr - 1, 0), Hn - 1);
        int gx = min(max(bx + pc - 1, 0), Wn - 1);
        smFB[i] = f2bf(fbb[(size_t)c * HW + gy * Wn + gx]);
    }
    __syncthreads();

    float acc[32];
#pragma unroll
    for (int s = 0; s < 32; ++s) acc[s] = 0.f;

#pragma unroll
    for (int chunk = 0; chunk < 9; ++chunk) {
        // GEMM: rows chunk*64 + wr*32 + [0,32), px wc*64 + [0,64), K=64
        f32x4 ka[2][4];
#pragma unroll
        for (int m = 0; m < 2; ++m)
#pragma unroll
            for (int n = 0; n < 4; ++n) ka[m][n] = f32x4{0.f, 0.f, 0.f, 0.f};
#pragma unroll
        for (int kk = 0; kk < 2; ++kk) {
            bf16x8 a[2];
#pragma unroll
            for (int m = 0; m < 2; ++m)
                a[m] = *(const bf16x8*)(G2p +
                        (size_t)(chunk * 64 + wr * 32 + m * 16 + lx) * 64 + kk * 32 + ls * 8);
#pragma unroll
            for (int n = 0; n < 4; ++n) {
                bf16x8 bv = *(const bf16x8*)(smH + ((kk * 4 + ls) * 128 + wc * 64 + n * 16 + lx) * 8);
#pragma unroll
                for (int m = 0; m < 2; ++m)
                    ka[m][n] = __builtin_amdgcn_mfma_f32_16x16x32_bf16(a[m], bv, ka[m][n], 0, 0, 0);
            }
        }
        // epilogue: + g2b, write swizzled smK[chunk&1]
        unsigned short* K = smK[chunk & 1];
#pragma unroll
        for (int m = 0; m < 2; ++m) {
            const float4 bb4 = *(const float4*)(g2b + chunk * 64 + wr * 32 + m * 16 + ls * 4);
            const float bb[4] = {bb4.x, bb4.y, bb4.z, bb4.w};
#pragma unroll
            for (int n = 0; n < 4; ++n) {
                const int pxl = wc * 64 + n * 16 + lx;
                const int base = (pxl >> 1) ^ (ls << 3);   // swizzle key = (rl>>2)&3 = ls
#pragma unroll
                for (int j = 0; j < 4; ++j) {
                    const int rl = wr * 32 + m * 16 + ls * 4 + j;
                    K[rl * 128 + base * 2 + (pxl & 1)] = f2bf(ka[m][n][j] + bb[j]);
                }
            }
        }
        __syncthreads();
        // apply: rows of this chunk whose channel parity == chalf
        const unsigned short* Kr = smK[chunk & 1];
#pragma unroll
        for (int rl = 0; rl < 64; ++rl) {
            const int r = chunk * 64 + rl;         // compile-time
            const int c = r / 9, t = r - c * 9;    // compile-time
            const int s = c >> 1;
            if ((c & 1) == chalf) {
                float kv = bf2f(Kr[rl * 128 +
                                   ((((px >> 1) ^ (((rl >> 2) & 3) << 3)) << 1) | (px & 1))]);
                float pv = bf2f(smFB[c * 180 + (ty + t / 3) * 18 + tx + (t % 3)]);
                acc[s] = fmaf(kv, pv, acc[s]);
            }
        }
    }

    // out = fb (fp32 residual) + dynconv
    const int pxg = (by + ty) * Wn + bx + tx;
#pragma unroll
    for (int s = 0; s < 32; ++s) {
        const int c = 2 * s + chalf;
        out[(size_t)b * CHW + (size_t)c * HW + pxg] = fbb[(size_t)c * HW + pxg] + acc[s];
    }
}

// ---------------- final fusion via MFMA: out = Fw @ concat(fe*(1+sc), fb2) -----
// Block: 128 co x 128 px, K=128. A-frags from global Fwp, B from 32 KB LDS.
__global__ __launch_bounds__(256, 2) void fuse_mfma_k(
        const float* __restrict__ fe, const float* __restrict__ scale,
        const float* __restrict__ fb2, const unsigned short* __restrict__ Fwp,
        float* __restrict__ out) {
    __shared__ unsigned short smF[16384];   // [oct16][px128][8ci] 32 KB
    const int bid = blockIdx.x;
    const int b = bid >> 7, px0 = (bid & 127) << 7;
    const int tid = threadIdx.x;
    const int lane = tid & 63, w = tid >> 6;
    const int lx = lane & 15, ls = lane >> 4;
    const int wr = w & 1, wc = w >> 1;
    const float* feb = fe  + (size_t)b * CHW + px0;
    const float* fbb = fb2 + (size_t)b * CHW + px0;
    const float* sc  = scale + b * HW + px0;

#pragma unroll
    for (int it = 0; it < 32; ++it) {
        int slot = tid + it * 256;
        int c2 = slot >> 7, pxl = slot & 127;
        float v0, v1;
        if (c2 < 32) {
            float s = 1.f + sc[pxl];
            v0 = feb[(size_t)(2 * c2) * HW + pxl] * s;
            v1 = feb[(size_t)(2 * c2 + 1) * HW + pxl] * s;
        } else {
            v0 = fbb[(size_t)(2 * c2 - 64) * HW + pxl];
            v1 = fbb[(size_t)(2 * c2 - 63) * HW + pxl];
        }
        ((unsigned*)smF)[(c2 >> 2) * 512 + pxl * 4 + (c2 & 3)] =
            (unsigned)f2bf(v0) | ((unsigned)f2bf(v1) << 16);
    }
    __syncthreads();

    f32x4 acc[4][4];
#pragma unroll
    for (int m = 0; m < 4; ++m)
#pragma unroll
        for (int n = 0; n < 4; ++n) acc[m][n] = f32x4{0.f, 0.f, 0.f, 0.f};

#pragma unroll
    for (int kk = 0; kk < 4; ++kk) {
        bf16x8 a[4];
#pragma unroll
        for (int m = 0; m < 4; ++m)
            a[m] = *(const bf16x8*)(Fwp + (size_t)(wr * 64 + m * 16 + lx) * 128 + kk * 32 + ls * 8);
#pragma unroll
        for (int n = 0; n < 4; ++n) {
            bf16x8 bv = *(const bf16x8*)(smF + ((kk * 4 + ls) * 128 + wc * 64 + n * 16 + lx) * 8);
#pragma unroll
            for (int m = 0; m < 4; ++m)
                acc[m][n] = __builtin_amdgcn_mfma_f32_16x16x32_bf16(a[m], bv, acc[m][n], 0, 0, 0);
        }
    }

    const size_t ob = (size_t)b * 2 * CHW + px0 + wc * 64;
#pragma unroll
    for (int m = 0; m < 4; ++m)
#pragma unroll
        for (int n = 0; n < 4; ++n)
#pragma unroll
            for (int j = 0; j < 4; ++j) {
                const int co = wr * 64 + m * 16 + ls * 4 + j;
                out[ob + (size_t)co * HW + n * 16 + lx] = acc[m][n][j];
            }
}

// ---------------- mean over H,W per (b,c) ----------------
__global__ void mean_hw_k(const float* __restrict__ in, float* __restrict__ w0) {
    int bc = blockIdx.x;
    const float* p = in + (size_t)bc * HW;
    float s = 0.f;
    for (int i = threadIdx.x; i < HW; i += 256) s += p[i];
#pragma unroll
    for (int off = 32; off; off >>= 1) s += __shfl_down(s, off);
    __shared__ float ws4[4];
    if ((threadIdx.x & 63) == 0) ws4[threadIdx.x >> 6] = s;
    __syncthreads();
    if (threadIdx.x == 0)
        w0[bc] = (ws4[0] + ws4[1] + ws4[2] + ws4[3]) * (1.f / 16384.f);
}

// ---------------- SE MLP ----------------
__global__ void mlp_k(const float* __restrict__ w0, const float* __restrict__ A1,
                      const float* __restrict__ b1, const float* __restrict__ A2,
                      const float* __restrict__ b2, float* __restrict__ w0s) {
    int b = blockIdx.x, t = threadIdx.x;       // 128 threads
    __shared__ float w0r[64], hid[128];
    if (t < 64) w0r[t] = w0[b * 64 + t];
    __syncthreads();
    float s = b1[t];
    for (int c = 0; c < 64; ++c) s = fmaf(A1[t * 64 + c], w0r[c], s);
    hid[t] = fmaxf(s, 0.f);
    __syncthreads();
    if (t < 64) {
        float s2 = b2[t];
        for (int j = 0; j < 128; ++j) s2 = fmaf(A2[t * 128 + j], hid[j], s2);
        w0s[b * 64 + t] = 1.f / (1.f + expf(-s2));
    }
}

// ---------------- rgb gate: conv1x1 C->1 + bias ----------------
__global__ void rgb_k(const float* __restrict__ f2, const float* __restrict__ Rw,
                      const float* __restrict__ rb, float* __restrict__ rgb) {
    int by = blockIdx.x;
    int b = by >> 7, y = by & 127;
    int x = threadIdx.x;
    const float* p = f2 + (size_t)b * CHW + y * Wn + x;
    float s = rb[0];
    for (int c = 0; c < 64; ++c) s = fmaf(Rw[c], p[c * HW], s);
    rgb[by * Wn + x] = s;
}

// ---------------- f_b1 = f_blur * (1+w0s) * (1+rgb) ----------------
__global__ void fb1_k(const float4* __restrict__ fblur, const float* __restrict__ w0s,
                      const float4* __restrict__ rgb, float4* __restrict__ o) {
    int i = blockIdx.x * blockDim.x + threadIdx.x;
    int b = i >> 18;
    int c = (i >> 12) & 63;
    int pix4 = i & 4095;
    float s = 1.f + w0s[b * 64 + c];
    float4 f = fblur[i];
    float4 r = rgb[(b << 12) + pix4];
    o[i] = make_float4(f.x * s * (1.f + r.x), f.y * s * (1.f + r.y),
                       f.z * s * (1.f + r.z), f.w * s * (1.f + r.w));
}

// ---------------- channel max/mean -> comp[B,2,H,W] ----------------
__global__ void comp_k(const float* __restrict__ sa, float* __restrict__ comp) {
    int by = blockIdx.x;
    int b = by >> 7, y = by & 127;
    int x = threadIdx.x;
    const float* p = sa + (size_t)b * CHW + y * Wn + x;
    float mx = p[0], sm = p[0];
    for (int c = 1; c < 64; ++c) { float v = p[c * HW]; mx = fmaxf(mx, v); sm += v; }
    float* cb = comp + (size_t)b * 2 * HW + y * Wn + x;
    cb[0]  = mx;
    cb[HW] = sm * (1.f / 64.f);
}

// ---------------- spatial 5x5 conv (2->1, pad 2, zero) + sigmoid ----------------
__global__ void sconv5_k(const float* __restrict__ comp, const float* __restrict__ Ew,
                         const float* __restrict__ eb, float* __restrict__ scale) {
    int id = blockIdx.x * 256 + threadIdx.x;
    int b = id >> 14, p = id & 16383;
    int y = p >> 7, x = p & 127;
    const float* cb = comp + (size_t)b * 2 * HW;
    float acc = eb[0];
#pragma unroll
    for (int ch = 0; ch < 2; ++ch)
#pragma unroll
        for (int ky = 0; ky < 5; ++ky) {
            int gy = y + ky - 2;
            if ((unsigned)gy >= (unsigned)Hn) continue;
#pragma unroll
            for (int kx = 0; kx < 5; ++kx) {
                int gx = x + kx - 2;
                if ((unsigned)gx >= (unsigned)Wn) continue;
                acc = fmaf(Ew[ch * 25 + ky * 5 + kx], cb[ch * HW + gy * Wn + gx], acc);
            }
        }
    scale[id] = 1.f / (1.f + expf(-acc));
}

// ---------------- host launch ----------------
extern "C" void kernel_launch(void* const* d_in, const int* in_sizes, int n_in,
                              void* d_out, int out_size, void* d_ws, size_t ws_size,
                              hipStream_t stream) {
    const float* f_event = (const float*)d_in[0];
    const float* f_blur  = (const float*)d_in[1];
    const float* Wt1 = (const float*)d_in[2];
    const float* Wt2 = (const float*)d_in[3];
    const float* Wt3 = (const float*)d_in[4];
    const float* A1  = (const float*)d_in[5];
    const float* b1  = (const float*)d_in[6];
    const float* A2  = (const float*)d_in[7];
    const float* b2  = (const float*)d_in[8];
    const float* G1  = (const float*)d_in[9];
    const float* g1b = (const float*)d_in[10];
    const float* G2  = (const float*)d_in[11];
    const float* g2b = (const float*)d_in[12];
    const float* Rw  = (const float*)d_in[13];
    const float* rb  = (const float*)d_in[14];
    const float* S1  = (const float*)d_in[15];
    const float* S2  = (const float*)d_in[16];
    const float* Ew  = (const float*)d_in[17];
    const float* eb  = (const float*)d_in[18];
    const float* Fw  = (const float*)d_in[19];
    float* out = (float*)d_out;

    float* ws   = (float*)d_ws;
    float* bufA = ws;
    float* bufB = ws + (size_t)Bn * CHW;
    float* bufC = ws + (size_t)2 * Bn * CHW;
    float* w0    = ws + (size_t)3 * Bn * CHW;
    float* w0s   = w0 + 512;
    float* rgb   = w0s + 512;
    float* comp  = rgb + Bn * HW;
    float* scale = comp + 2 * Bn * HW;
    unsigned short* wprep = (unsigned short*)(scale + Bn * HW);  // 6 x 36864 bf16
    unsigned short* G2p = wprep + 6 * 36864;                     // 576x64 bf16
    unsigned short* Fwp = G2p + 36864;                           // 128x128 bf16

    dim3 cgrid(Wn / 16, Hn / 16, Bn);          // 8x8x8
    const int n4 = Bn * CHW / 4;

    // 0. weight preps
    prep_w_k<<<dim3(144, 6), 256, 0, stream>>>(Wt1, Wt2, Wt3, G1, S1, S2, wprep);
    prep2_k<<<208, 256, 0, stream>>>(G2, Fw, G2p, Fwp);
    // 1. fused0 = f_event + f_blur
    add_k<<<n4 / 256, 256, 0, stream>>>((const float4*)f_event, (const float4*)f_blur,
                                        (float4*)bufA, n4);
    // 2. B = relu(conv(A, Wt1))
    conv3x3_mfma<true, false, false><<<cgrid, 256, 0, stream>>>(bufA, wprep + 0 * 36864, nullptr, bufB);
    // 3. A = conv(B, Wt2)  -> "fused"
    conv3x3_mfma<false, false, false><<<cgrid, 256, 0, stream>>>(bufB, wprep + 1 * 36864, nullptr, bufA);
    // 4. SE gate
    mean_hw_k<<<Bn * Cn, 256, 0, stream>>>(bufA, w0);
    mlp_k<<<Bn, 128, 0, stream>>>(w0, A1, b1, A2, b2, w0s);
    // 5. B = A + relu(conv(A, Wt3)) -> fused2
    conv3x3_mfma<true, false, true><<<cgrid, 256, 0, stream>>>(bufA, wprep + 2 * 36864, nullptr, bufB);
    // 6. rgb gate from fused2
    rgb_k<<<Bn * Hn, Wn, 0, stream>>>(bufB, Rw, rb, rgb);
    // 7. C = f_blur * (1+w0s) * (1+rgb)  -> f_b1
    fb1_k<<<n4 / 256, 256, 0, stream>>>((const float4*)f_blur, w0s,
                                        (const float4*)rgb, (float4*)bufC);
    // 8. A = relu(conv(f_event, G1) + g1b)  -> h
    conv3x3_mfma<true, true, false><<<cgrid, 256, 0, stream>>>(f_event, wprep + 3 * 36864, g1b, bufA);
    // 9. B = C + dynconv(C, kern(A))  -> f_b2  (single fused launch, all batches)
    dynfused_k<<<dim3(8, 16, 8), 256, 0, stream>>>(bufC, bufA, G2p, g2b, bufB);
    // 10. sa = conv(relu(conv(f_event,S1)), S2)
    conv3x3_mfma<true, false, false><<<cgrid, 256, 0, stream>>>(f_event, wprep + 4 * 36864, nullptr, bufA);
    conv3x3_mfma<false, false, false><<<cgrid, 256, 0, stream>>>(bufA, wprep + 5 * 36864, nullptr, bufC);
    // 11. comp + 5x5 conv + sigmoid -> scale_e
    comp_k<<<Bn * Hn, Wn, 0, stream>>>(bufC, comp);
    sconv5_k<<<Bn * HW / 256, 256, 0, stream>>>(comp, Ew, eb, scale);
    // 12. out = Fw @ concat(f_event*(1+scale_e), f_b2)   (MFMA)
    fuse_mfma_k<<<Bn * HW / 128, 256, 0, stream>>>(f_event, scale, bufB, Fwp, out);
}

// Round 7
// 382.816 us; speedup vs baseline: 8.2359x; 1.0497x over previous
//
#include <hip/hip_runtime.h>
#include <math.h>

constexpr int Bn = 8, Cn = 64, Hn = 128, Wn = 128;
constexpr int HW  = Hn * Wn;      // 16384
constexpr int CHW = Cn * HW;      // 1048576

typedef float  f32x4  __attribute__((ext_vector_type(4)));
typedef __bf16 bf16x8 __attribute__((ext_vector_type(8)));
typedef unsigned int u32x4 __attribute__((ext_vector_type(4)));
typedef unsigned int u32x2 __attribute__((ext_vector_type(2)));

static __device__ __forceinline__ unsigned short f2bf(float f) {
    unsigned u = __builtin_bit_cast(unsigned, f);
    u = (u + 0x7FFF + ((u >> 16) & 1)) >> 16;
    return (unsigned short)u;
}
static __device__ __forceinline__ float bf2f(unsigned short v) {
    unsigned u = (unsigned)v << 16;
    return __builtin_bit_cast(float, u);
}

// ---------------- weight prep: OIHW fp32 -> [h][s][t][co][8cj] bf16 ----------------
__global__ void prep_w_k(const float* __restrict__ W0, const float* __restrict__ W1,
                         const float* __restrict__ W2, const float* __restrict__ W3,
                         const float* __restrict__ W4, const float* __restrict__ W5,
                         unsigned short* __restrict__ dst) {
    int i = blockIdx.x * 256 + threadIdx.x;
    if (i >= 36864) return;
    const float* W = W0;
    switch (blockIdx.y) {
        case 1: W = W1; break; case 2: W = W2; break;
        case 3: W = W3; break; case 4: W = W4; break; case 5: W = W5; break;
        default: break;
    }
    int cj = i & 7;
    int rest = i >> 3;
    int co = rest & 63;
    rest >>= 6;              // (h*4+s)*9 + t
    int t  = rest % 9;
    int hs = rest / 9;       // 0..7
    int ci = hs * 8 + cj;
    dst[(size_t)blockIdx.y * 36864 + i] = f2bf(W[(co * 64 + ci) * 9 + t]);
}

// ---------------- prep2: G2 [576x64] and Fw [128x128] -> bf16 row-major --------
__global__ void prep2_k(const float* __restrict__ G2, const float* __restrict__ Fw,
                        unsigned short* __restrict__ G2p, unsigned short* __restrict__ Fwp) {
    int i = blockIdx.x * 256 + threadIdx.x;
    if (i < 36864) G2p[i] = f2bf(G2[i]);
    else if (i < 36864 + 16384) Fwp[i - 36864] = f2bf(Fw[i - 36864]);
}

// ---------------- conv3x3 via MFMA with fused epilogues ----------------
// RELU/BIAS/ADD_INPUT as before; ADD2: stage in+in2; RGB: gate = sum_c gw[c]*v + gb
// -> gout[b][y][x]; COMP: gout[b][{max,mean}][y][x]; STORE: write out tensor.
template<bool RELU, bool BIAS, bool ADD_INPUT, bool ADD2, bool RGB, bool COMP, bool STORE>
__global__ __launch_bounds__(256, 2) void conv3x3_mfma(
        const float* __restrict__ in, const float* __restrict__ in2,
        const unsigned short* __restrict__ Wp, const float* __restrict__ bias,
        float* __restrict__ out, const float* __restrict__ gw,
        const float* __restrict__ gb, float* __restrict__ gout) {
    __shared__ unsigned short smIn[10368];   // 4 x 324 x 8 = 20.25 KB
    __shared__ unsigned short smW[18432];    // 4 x 9 x 64 x 8 = 36 KB
    const int b  = blockIdx.z;
    const int by = blockIdx.y << 4, bx = blockIdx.x << 4;
    const int tid = threadIdx.x;
    const int lane = tid & 63, w = tid >> 6;
    const int lx = lane & 15, ls = lane >> 4;
    const float* inb = in + (size_t)b * CHW;
    const float* in2b = ADD2 ? (in2 + (size_t)b * CHW) : nullptr;

    f32x4 acc[4][4];
#pragma unroll
    for (int m = 0; m < 4; ++m)
#pragma unroll
        for (int n = 0; n < 4; ++n) acc[m][n] = f32x4{0.f, 0.f, 0.f, 0.f};

    for (int h = 0; h < 2; ++h) {
        __syncthreads();
        {
            const int cibase = h << 5;
            for (int idx = tid; idx < 5184; idx += 256) {
                int c2 = idx / 324;
                int p  = idx - c2 * 324;
                int yy = p / 18, xx = p - yy * 18;
                int gy = by + yy - 1, gx = bx + xx - 1;
                unsigned pk = 0;
                if ((unsigned)gy < (unsigned)Hn && (unsigned)gx < (unsigned)Wn) {
                    const size_t o = (size_t)(cibase + c2 * 2) * HW + gy * Wn + gx;
                    float v0 = inb[o], v1 = inb[o + HW];
                    if constexpr (ADD2) { v0 += in2b[o]; v1 += in2b[o + HW]; }
                    pk = (unsigned)f2bf(v0) | ((unsigned)f2bf(v1) << 16);
                }
                ((unsigned*)smIn)[(c2 >> 2) * 1296 + p * 4 + (c2 & 3)] = pk;
            }
        }
        {
            const u32x4* src = (const u32x4*)(Wp + h * 18432);
            u32x4* dst = (u32x4*)smW;
            for (int i = tid; i < 2304; i += 256) dst[i] = src[i];
        }
        __syncthreads();

#pragma unroll
        for (int ky = 0; ky < 3; ++ky)
#pragma unroll
        for (int kx = 0; kx < 3; ++kx) {
            const int t = ky * 3 + kx;
            bf16x8 a[4];
            const unsigned short* wbase = smW + ls * 4608 + t * 512 + lx * 8;
#pragma unroll
            for (int m = 0; m < 4; ++m)
                a[m] = *(const bf16x8*)(wbase + m * 128);
            const unsigned short* ibase =
                smIn + ls * 2592 + (((4 * w + ky) * 18) + lx + kx) * 8;
#pragma unroll
            for (int n = 0; n < 4; ++n) {
                bf16x8 bf = *(const bf16x8*)(ibase + n * 144);
#pragma unroll
                for (int m = 0; m < 4; ++m)
                    acc[m][n] = __builtin_amdgcn_mfma_f32_16x16x32_bf16(
                        a[m], bf, acc[m][n], 0, 0, 0);
            }
        }
    }

    // epilogue
    const int y0 = by + 4 * w;
    const size_t outb = (size_t)b * CHW;
    float gs[4], gm[4];
    if constexpr (RGB || COMP) {
#pragma unroll
        for (int n = 0; n < 4; ++n) { gs[n] = 0.f; gm[n] = -1e30f; }
    }
#pragma unroll
    for (int m = 0; m < 4; ++m) {
        float4 rw4;
        if constexpr (RGB) rw4 = *(const float4*)(gw + 16 * m + ls * 4);
        const float rwf[4] = {RGB ? rw4.x : 0.f, RGB ? rw4.y : 0.f,
                              RGB ? rw4.z : 0.f, RGB ? rw4.w : 0.f};
#pragma unroll
        for (int r = 0; r < 4; ++r) {
            const int co = 16 * m + ls * 4 + r;
            float bv = 0.f;
            if constexpr (BIAS) bv = bias[co];
#pragma unroll
            for (int n = 0; n < 4; ++n) {
                float v = acc[m][n][r] + bv;
                if constexpr (RELU) v = fmaxf(v, 0.f);
                const size_t off = outb + (size_t)co * HW + (size_t)(y0 + n) * Wn + bx + lx;
                if constexpr (ADD_INPUT) v += in[off];
                if constexpr (STORE) out[off] = v;
                if constexpr (RGB) gs[n] = fmaf(rwf[r], v, gs[n]);
                if constexpr (COMP) { gm[n] = fmaxf(gm[n], v); gs[n] += v; }
            }
        }
    }
    if constexpr (RGB) {
#pragma unroll
        for (int n = 0; n < 4; ++n) {
            float s = gs[n];
            s += __shfl_xor(s, 16);
            s += __shfl_xor(s, 32);
            if (ls == 0)
                gout[(size_t)b * HW + (size_t)(y0 + n) * Wn + bx + lx] = s + gb[0];
        }
    }
    if constexpr (COMP) {
#pragma unroll
        for (int n = 0; n < 4; ++n) {
            float s = gs[n], mx = gm[n];
            s += __shfl_xor(s, 16);
            s += __shfl_xor(s, 32);
            mx = fmaxf(mx, __shfl_xor(mx, 16));
            mx = fmaxf(mx, __shfl_xor(mx, 32));
            if (ls == 0) {
                const size_t o = (size_t)b * 2 * HW + (size_t)(y0 + n) * Wn + bx + lx;
                gout[o]      = mx;
                gout[o + HW] = s * (1.f / 64.f);
            }
        }
    }
}

// ---------------- f_b1 = f_blur * (1+w0s) * (1+rgb) ----------------
__global__ void fb1_k(const float4* __restrict__ fblur, const float* __restrict__ w0s,
                      const float4* __restrict__ rgb, float4* __restrict__ o) {
    int i = blockIdx.x * blockDim.x + threadIdx.x;
    int b = i >> 18;
    int c = (i >> 12) & 63;
    int pix4 = i & 4095;
    float s = 1.f + w0s[b * 64 + c];
    float4 f = fblur[i];
    float4 r = rgb[(b << 12) + pix4];
    o[i] = make_float4(f.x * s * (1.f + r.x), f.y * s * (1.f + r.y),
                       f.z * s * (1.f + r.z), f.w * s * (1.f + r.w));
}

// ---------------- fused dynamic conv (round-5 verified version) --------------
// Block: 16x8 px tile (128 px), 4 waves. Thread = 1 px x channel-parity half.
// Per chunk (64 kern rows): GEMM (a-frags from global G2p, b-frags from smH),
// epilogue -> XOR-swizzled smK (double-buffered), barrier, unrolled apply.
__global__ __launch_bounds__(256, 2) void dynfused_k(
        const float* __restrict__ fb, const float* __restrict__ h,
        const unsigned short* __restrict__ G2p, const float* __restrict__ g2b,
        float* __restrict__ out) {
    __shared__ unsigned short smH[8192];       // [oct8][px128][8ci] 16 KB
    __shared__ unsigned short smFB[11520];     // [c64][p180] 22.5 KB (10x18 patch)
    __shared__ unsigned short smK[2][8192];    // dbuf [r64][px128 swz] 2x16 KB
    const int b  = blockIdx.z;
    const int by = blockIdx.y << 3, bx = blockIdx.x << 4;
    const int tid = threadIdx.x;
    const int lane = tid & 63, w = tid >> 6;
    const int lx = lane & 15, ls = lane >> 4;
    const int wr = w & 1, wc = w >> 1;
    const int px = tid & 127;
    const int chalf = __builtin_amdgcn_readfirstlane(tid >> 7);  // wave-uniform
    const int ty = px >> 4, tx = px & 15;

    const float* fbb = fb + (size_t)b * CHW;
    const float* hb  = h + (size_t)b * CHW;

    // stage h: 64ci x 128px -> [oct][px][8]
#pragma unroll
    for (int it = 0; it < 4; ++it) {
        int i = tid + it * 256;
        int p = i & 127, oct = i >> 7;
        const float* sp = hb + (size_t)oct * 8 * HW + (by + (p >> 4)) * Wn + bx + (p & 15);
        unsigned short v[8];
#pragma unroll
        for (int j = 0; j < 8; ++j) v[j] = f2bf(sp[(size_t)j * HW]);
        u32x4 pk;
        pk[0] = (unsigned)v[0] | ((unsigned)v[1] << 16);
        pk[1] = (unsigned)v[2] | ((unsigned)v[3] << 16);
        pk[2] = (unsigned)v[4] | ((unsigned)v[5] << 16);
        pk[3] = (unsigned)v[6] | ((unsigned)v[7] << 16);
        ((u32x4*)smH)[oct * 128 + p] = pk;
    }
    // stage fb patch: 64ch x 10x18, edge-clamped
    for (int i = tid; i < 11520; i += 256) {
        int c = i / 180, p = i - c * 180;
        int pr = p / 18, pc = p - pr * 18;
        int gy = min(max(by + pr - 1, 0), Hn - 1);
        int gx = min(max(bx + pc - 1, 0), Wn - 1);
        smFB[i] = f2bf(fbb[(size_t)c * HW + gy * Wn + gx]);
    }
    __syncthreads();

    float acc[32];
#pragma unroll
    for (int s = 0; s < 32; ++s) acc[s] = 0.f;

#pragma unroll
    for (int chunk = 0; chunk < 9; ++chunk) {
        // GEMM: rows chunk*64 + wr*32 + [0,32), px wc*64 + [0,64), K=64
        f32x4 ka[2][4];
#pragma unroll
        for (int m = 0; m < 2; ++m)
#pragma unroll
            for (int n = 0; n < 4; ++n) ka[m][n] = f32x4{0.f, 0.f, 0.f, 0.f};
#pragma unroll
        for (int kk = 0; kk < 2; ++kk) {
            bf16x8 a[2];
#pragma unroll
            for (int m = 0; m < 2; ++m)
                a[m] = *(const bf16x8*)(G2p +
                        (size_t)(chunk * 64 + wr * 32 + m * 16 + lx) * 64 + kk * 32 + ls * 8);
#pragma unroll
            for (int n = 0; n < 4; ++n) {
                bf16x8 bv = *(const bf16x8*)(smH + ((kk * 4 + ls) * 128 + wc * 64 + n * 16 + lx) * 8);
#pragma unroll
                for (int m = 0; m < 2; ++m)
                    ka[m][n] = __builtin_amdgcn_mfma_f32_16x16x32_bf16(a[m], bv, ka[m][n], 0, 0, 0);
            }
        }
        // epilogue: + g2b, write swizzled smK[chunk&1]
        unsigned short* K = smK[chunk & 1];
#pragma unroll
        for (int m = 0; m < 2; ++m) {
            const float4 bb4 = *(const float4*)(g2b + chunk * 64 + wr * 32 + m * 16 + ls * 4);
            const float bb[4] = {bb4.x, bb4.y, bb4.z, bb4.w};
#pragma unroll
            for (int n = 0; n < 4; ++n) {
                const int pxl = wc * 64 + n * 16 + lx;
                const int base = (pxl >> 1) ^ (ls << 3);   // swizzle key = (rl>>2)&3 = ls
#pragma unroll
                for (int j = 0; j < 4; ++j) {
                    const int rl = wr * 32 + m * 16 + ls * 4 + j;
                    K[rl * 128 + base * 2 + (pxl & 1)] = f2bf(ka[m][n][j] + bb[j]);
                }
            }
        }
        __syncthreads();
        // apply: rows of this chunk whose channel parity == chalf
        const unsigned short* Kr = smK[chunk & 1];
#pragma unroll
        for (int rl = 0; rl < 64; ++rl) {
            const int r = chunk * 64 + rl;         // compile-time
            const int c = r / 9, t = r - c * 9;    // compile-time
            const int s = c >> 1;
            if ((c & 1) == chalf) {
                float kv = bf2f(Kr[rl * 128 +
                                   ((((px >> 1) ^ (((rl >> 2) & 3) << 3)) << 1) | (px & 1))]);
                float pv = bf2f(smFB[c * 180 + (ty + t / 3) * 18 + tx + (t % 3)]);
                acc[s] = fmaf(kv, pv, acc[s]);
            }
        }
    }

    // out = fb (fp32 residual) + dynconv
    const int pxg = (by + ty) * Wn + bx + tx;
#pragma unroll
    for (int s = 0; s < 32; ++s) {
        const int c = 2 * s + chalf;
        out[(size_t)b * CHW + (size_t)c * HW + pxg] = fbb[(size_t)c * HW + pxg] + acc[s];
    }
}

// ---------------- final fusion via MFMA ----------------
__global__ __launch_bounds__(256, 2) void fuse_mfma_k(
        const float* __restrict__ fe, const float* __restrict__ scale,
        const float* __restrict__ fb2, const unsigned short* __restrict__ Fwp,
        float* __restrict__ out) {
    __shared__ unsigned short smF[16384];   // [oct16][px128][8ci] 32 KB
    const int bid = blockIdx.x;
    const int b = bid >> 7, px0 = (bid & 127) << 7;
    const int tid = threadIdx.x;
    const int lane = tid & 63, w = tid >> 6;
    const int lx = lane & 15, ls = lane >> 4;
    const int wr = w & 1, wc = w >> 1;
    const float* feb = fe  + (size_t)b * CHW + px0;
    const float* fbb = fb2 + (size_t)b * CHW + px0;
    const float* sc  = scale + b * HW + px0;

#pragma unroll
    for (int it = 0; it < 32; ++it) {
        int slot = tid + it * 256;
        int c2 = slot >> 7, pxl = slot & 127;
        float v0, v1;
        if (c2 < 32) {
            float s = 1.f + sc[pxl];
            v0 = feb[(size_t)(2 * c2) * HW + pxl] * s;
            v1 = feb[(size_t)(2 * c2 + 1) * HW + pxl] * s;
        } else {
            v0 = fbb[(size_t)(2 * c2 - 64) * HW + pxl];
            v1 = fbb[(size_t)(2 * c2 - 63) * HW + pxl];
        }
        ((unsigned*)smF)[(c2 >> 2) * 512 + pxl * 4 + (c2 & 3)] =
            (unsigned)f2bf(v0) | ((unsigned)f2bf(v1) << 16);
    }
    __syncthreads();

    f32x4 acc[4][4];
#pragma unroll
    for (int m = 0; m < 4; ++m)
#pragma unroll
        for (int n = 0; n < 4; ++n) acc[m][n] = f32x4{0.f, 0.f, 0.f, 0.f};

#pragma unroll
    for (int kk = 0; kk < 4; ++kk) {
        bf16x8 a[4];
#pragma unroll
        for (int m = 0; m < 4; ++m)
            a[m] = *(const bf16x8*)(Fwp + (size_t)(wr * 64 + m * 16 + lx) * 128 + kk * 32 + ls * 8);
#pragma unroll
        for (int n = 0; n < 4; ++n) {
            bf16x8 bv = *(const bf16x8*)(smF + ((kk * 4 + ls) * 128 + wc * 64 + n * 16 + lx) * 8);
#pragma unroll
            for (int m = 0; m < 4; ++m)
                acc[m][n] = __builtin_amdgcn_mfma_f32_16x16x32_bf16(a[m], bv, acc[m][n], 0, 0, 0);
        }
    }

    const size_t ob = (size_t)b * 2 * CHW + px0 + wc * 64;
#pragma unroll
    for (int m = 0; m < 4; ++m)
#pragma unroll
        for (int n = 0; n < 4; ++n)
#pragma unroll
            for (int j = 0; j < 4; ++j) {
                const int co = wr * 64 + m * 16 + ls * 4 + j;
                out[ob + (size_t)co * HW + n * 16 + lx] = acc[m][n][j];
            }
}

// ---------------- mean over H,W per (b,c) ----------------
__global__ void mean_hw_k(const float* __restrict__ in, float* __restrict__ w0) {
    int bc = blockIdx.x;
    const float* p = in + (size_t)bc * HW;
    float s = 0.f;
    for (int i = threadIdx.x; i < HW; i += 256) s += p[i];
#pragma unroll
    for (int off = 32; off; off >>= 1) s += __shfl_down(s, off);
    __shared__ float ws4[4];
    if ((threadIdx.x & 63) == 0) ws4[threadIdx.x >> 6] = s;
    __syncthreads();
    if (threadIdx.x == 0)
        w0[bc] = (ws4[0] + ws4[1] + ws4[2] + ws4[3]) * (1.f / 16384.f);
}

// ---------------- SE MLP ----------------
__global__ void mlp_k(const float* __restrict__ w0, const float* __restrict__ A1,
                      const float* __restrict__ b1, const float* __restrict__ A2,
                      const float* __restrict__ b2, float* __restrict__ w0s) {
    int b = blockIdx.x, t = threadIdx.x;       // 128 threads
    __shared__ float w0r[64], hid[128];
    if (t < 64) w0r[t] = w0[b * 64 + t];
    __syncthreads();
    float s = b1[t];
    for (int c = 0; c < 64; ++c) s = fmaf(A1[t * 64 + c], w0r[c], s);
    hid[t] = fmaxf(s, 0.f);
    __syncthreads();
    if (t < 64) {
        float s2 = b2[t];
        for (int j = 0; j < 128; ++j) s2 = fmaf(A2[t * 128 + j], hid[j], s2);
        w0s[b * 64 + t] = 1.f / (1.f + expf(-s2));
    }
}

// ---------------- spatial 5x5 conv (2->1, pad 2, zero) + sigmoid ----------------
__global__ void sconv5_k(const float* __restrict__ comp, const float* __restrict__ Ew,
                         const float* __restrict__ eb, float* __restrict__ scale) {
    int id = blockIdx.x * 256 + threadIdx.x;
    int b = id >> 14, p = id & 16383;
    int y = p >> 7, x = p & 127;
    const float* cb = comp + (size_t)b * 2 * HW;
    float acc = eb[0];
#pragma unroll
    for (int ch = 0; ch < 2; ++ch)
#pragma unroll
        for (int ky = 0; ky < 5; ++ky) {
            int gy = y + ky - 2;
            if ((unsigned)gy >= (unsigned)Hn) continue;
#pragma unroll
            for (int kx = 0; kx < 5; ++kx) {
                int gx = x + kx - 2;
                if ((unsigned)gx >= (unsigned)Wn) continue;
                acc = fmaf(Ew[ch * 25 + ky * 5 + kx], cb[ch * HW + gy * Wn + gx], acc);
            }
        }
    scale[id] = 1.f / (1.f + expf(-acc));
}

// ---------------- host launch ----------------
extern "C" void kernel_launch(void* const* d_in, const int* in_sizes, int n_in,
                              void* d_out, int out_size, void* d_ws, size_t ws_size,
                              hipStream_t stream) {
    const float* f_event = (const float*)d_in[0];
    const float* f_blur  = (const float*)d_in[1];
    const float* Wt1 = (const float*)d_in[2];
    const float* Wt2 = (const float*)d_in[3];
    const float* Wt3 = (const float*)d_in[4];
    const float* A1  = (const float*)d_in[5];
    const float* b1  = (const float*)d_in[6];
    const float* A2  = (const float*)d_in[7];
    const float* b2  = (const float*)d_in[8];
    const float* G1  = (const float*)d_in[9];
    const float* g1b = (const float*)d_in[10];
    const float* G2  = (const float*)d_in[11];
    const float* g2b = (const float*)d_in[12];
    const float* Rw  = (const float*)d_in[13];
    const float* rb  = (const float*)d_in[14];
    const float* S1  = (const float*)d_in[15];
    const float* S2  = (const float*)d_in[16];
    const float* Ew  = (const float*)d_in[17];
    const float* eb  = (const float*)d_in[18];
    const float* Fw  = (const float*)d_in[19];
    float* out = (float*)d_out;

    float* ws   = (float*)d_ws;
    float* bufA = ws;
    float* bufB = ws + (size_t)Bn * CHW;
    float* bufC = ws + (size_t)2 * Bn * CHW;
    float* w0    = ws + (size_t)3 * Bn * CHW;
    float* w0s   = w0 + 512;
    float* rgb   = w0s + 512;
    float* comp  = rgb + Bn * HW;
    float* scale = comp + 2 * Bn * HW;
    unsigned short* wprep = (unsigned short*)(scale + Bn * HW);  // 6 x 36864 bf16
    unsigned short* G2p = wprep + 6 * 36864;                     // 576x64 bf16
    unsigned short* Fwp = G2p + 36864;                           // 128x128 bf16

    dim3 cgrid(Wn / 16, Hn / 16, Bn);          // 8x8x8
    const int n4 = Bn * CHW / 4;

    // 0. weight preps
    prep_w_k<<<dim3(144, 6), 256, 0, stream>>>(Wt1, Wt2, Wt3, G1, S1, S2, wprep);
    prep2_k<<<208, 256, 0, stream>>>(G2, Fw, G2p, Fwp);
    // 1. B = relu(conv(f_event + f_blur, Wt1))   [ADD2 fused]
    conv3x3_mfma<true, false, false, true, false, false, true><<<cgrid, 256, 0, stream>>>(
        f_event, f_blur, wprep + 0 * 36864, nullptr, bufB, nullptr, nullptr, nullptr);
    // 2. A = conv(B, Wt2) -> fused
    conv3x3_mfma<false, false, false, false, false, false, true><<<cgrid, 256, 0, stream>>>(
        bufB, nullptr, wprep + 1 * 36864, nullptr, bufA, nullptr, nullptr, nullptr);
    // 3. SE gate
    mean_hw_k<<<Bn * Cn, 256, 0, stream>>>(bufA, w0);
    mlp_k<<<Bn, 128, 0, stream>>>(w0, A1, b1, A2, b2, w0s);
    // 4. B = A + relu(conv(A, Wt3)) -> fused2, with fused rgb gate
    conv3x3_mfma<true, false, true, false, true, false, true><<<cgrid, 256, 0, stream>>>(
        bufA, nullptr, wprep + 2 * 36864, nullptr, bufB, Rw, rb, rgb);
    // 5. C = f_blur * (1+w0s) * (1+rgb)  -> f_b1
    fb1_k<<<n4 / 256, 256, 0, stream>>>((const float4*)f_blur, w0s,
                                        (const float4*)rgb, (float4*)bufC);
    // 6. A = relu(conv(f_event, G1) + g1b) -> h
    conv3x3_mfma<true, true, false, false, false, false, true><<<cgrid, 256, 0, stream>>>(
        f_event, nullptr, wprep + 3 * 36864, g1b, bufA, nullptr, nullptr, nullptr);
    // 7. B = C + dynconv(C, kern(A)) -> f_b2
    dynfused_k<<<dim3(8, 16, Bn), 256, 0, stream>>>(bufC, bufA, G2p, g2b, bufB);
    // 8. sa chain: C = relu(conv(f_event, S1)); comp from conv(C, S2) epilogue
    conv3x3_mfma<true, false, false, false, false, false, true><<<cgrid, 256, 0, stream>>>(
        f_event, nullptr, wprep + 4 * 36864, nullptr, bufC, nullptr, nullptr, nullptr);
    conv3x3_mfma<false, false, false, false, false, true, false><<<cgrid, 256, 0, stream>>>(
        bufC, nullptr, wprep + 5 * 36864, nullptr, bufA, nullptr, nullptr, comp);
    // 9. scale_e = sigmoid(conv5x5(comp))
    sconv5_k<<<Bn * HW / 256, 256, 0, stream>>>(comp, Ew, eb, scale);
    // 10. out = Fw @ concat(f_event*(1+scale_e), f_b2)
    fuse_mfma_k<<<Bn * HW / 128, 256, 0, stream>>>(f_event, scale, bufB, Fwp, out);
}

// Round 8
// 255.705 us; speedup vs baseline: 12.3300x; 1.4971x over previous
//
#include <hip/hip_runtime.h>
#include <math.h>

constexpr int Bn = 8, Cn = 64, Hn = 128, Wn = 128;
constexpr int HW  = Hn * Wn;      // 16384
constexpr int CHW = Cn * HW;      // 1048576
constexpr size_t NB = (size_t)Bn * CHW;   // elems per blocked tensor

typedef float  f32x4  __attribute__((ext_vector_type(4)));
typedef __bf16 bf16x8 __attribute__((ext_vector_type(8)));
typedef unsigned int u32x4 __attribute__((ext_vector_type(4)));
typedef unsigned int u32x2 __attribute__((ext_vector_type(2)));

static __device__ __forceinline__ unsigned short f2bf(float f) {
    unsigned u = __builtin_bit_cast(unsigned, f);
    u = (u + 0x7FFF + ((u >> 16) & 1)) >> 16;
    return (unsigned short)u;
}
static __device__ __forceinline__ float bf2f(unsigned short v) {
    unsigned u = (unsigned)v << 16;
    return __builtin_bit_cast(float, u);
}
static __device__ __forceinline__ float bfhalf(unsigned u, int hi) {
    unsigned r = hi ? (u & 0xffff0000u) : (u << 16);
    return __builtin_bit_cast(float, r);
}

// ---------------- weight prep: OIHW fp32 -> [kk][s][t][co][8cj] bf16 ----------------
__global__ void prep_w_k(const float* __restrict__ W0, const float* __restrict__ W1,
                         const float* __restrict__ W2, const float* __restrict__ W3,
                         const float* __restrict__ W4, const float* __restrict__ W5,
                         unsigned short* __restrict__ dst) {
    int i = blockIdx.x * 256 + threadIdx.x;
    if (i >= 36864) return;
    const float* W = W0;
    switch (blockIdx.y) {
        case 1: W = W1; break; case 2: W = W2; break;
        case 3: W = W3; break; case 4: W = W4; break; case 5: W = W5; break;
        default: break;
    }
    int cj = i & 7;
    int rest = i >> 3;
    int co = rest & 63;
    rest >>= 6;              // (kk*4+s)*9 + t
    int t  = rest % 9;
    int hs = rest / 9;       // 0..7
    int ci = hs * 8 + cj;
    dst[(size_t)blockIdx.y * 36864 + i] = f2bf(W[(co * 64 + ci) * 9 + t]);
}

// ---------------- prep2: G2 [576x64] and Fw [128x128] -> bf16 row-major --------
__global__ void prep2_k(const float* __restrict__ G2, const float* __restrict__ Fw,
                        unsigned short* __restrict__ G2p, unsigned short* __restrict__ Fwp) {
    int i = blockIdx.x * 256 + threadIdx.x;
    if (i < 36864) G2p[i] = f2bf(G2[i]);
    else if (i < 36864 + 16384) Fwp[i - 36864] = f2bf(Fw[i - 36864]);
}

// ---------------- pre: f_event -> evblk; f_event+f_blur -> f0blk (blocked bf16) ----
__global__ void pre_blk_k(const float* __restrict__ fe, const float* __restrict__ fb,
                          unsigned short* __restrict__ evb, unsigned short* __restrict__ f0b) {
    int i = blockIdx.x * 256 + threadIdx.x;       // (b, oct, px)
    int px = i & 16383;
    int oct = (i >> 14) & 7;
    int b = i >> 17;
    const float* pe = fe + (size_t)b * CHW + (size_t)oct * 8 * HW + px;
    const float* pb = fb + (size_t)b * CHW + (size_t)oct * 8 * HW + px;
    u32x4 ev, f0;
#pragma unroll
    for (int q = 0; q < 4; ++q) {
        float e0 = pe[(size_t)(2 * q) * HW],     b0 = pb[(size_t)(2 * q) * HW];
        float e1 = pe[(size_t)(2 * q + 1) * HW], b1 = pb[(size_t)(2 * q + 1) * HW];
        ev[q] = (unsigned)f2bf(e0) | ((unsigned)f2bf(e1) << 16);
        f0[q] = (unsigned)f2bf(e0 + b0) | ((unsigned)f2bf(e1 + b1) << 16);
    }
    const size_t o = ((size_t)(b * 8 + oct) * HW + px) * 8;
    *(u32x4*)(evb + o) = ev;
    *(u32x4*)(f0b + o) = f0;
}

// ---------------- conv3x3 via MFMA, blocked bf16 in/out, zero pad=1 ----------------
// 16x16 px tile, 4 waves; K = 9 taps x 64 ci; a-frags from global wprep (L2-hot);
// input staged to LDS as [oct8][18][18][8] via b128 copies.
template<bool RELU, bool BIAS, bool ADD_INPUT, bool RGB, bool COMP, bool STORE>
__global__ __launch_bounds__(256, 3) void conv3x3_blk(
        const unsigned short* __restrict__ in, const unsigned short* __restrict__ Wg,
        const float* __restrict__ bias, unsigned short* __restrict__ out,
        const float* __restrict__ gw, const float* __restrict__ gb,
        float* __restrict__ gout) {
    __shared__ unsigned short smIn[20736];   // 8 x 324 x 8 = 40.5 KB
    const int b  = blockIdx.z;
    const int by = blockIdx.y << 4, bx = blockIdx.x << 4;
    const int tid = threadIdx.x;
    const int lane = tid & 63, w = tid >> 6;
    const int lx = lane & 15, ls = lane >> 4;

    for (int idx = tid; idx < 2592; idx += 256) {
        int oct = idx / 324;
        int p   = idx - oct * 324;
        int yy = p / 18, xx = p - yy * 18;
        int gy = by + yy - 1, gx = bx + xx - 1;
        u32x4 v = u32x4{0u, 0u, 0u, 0u};
        if ((unsigned)gy < (unsigned)Hn && (unsigned)gx < (unsigned)Wn)
            v = *(const u32x4*)(in + ((size_t)(b * 8 + oct) * HW + gy * Wn + gx) * 8);
        *(u32x4*)(smIn + idx * 8) = v;
    }
    __syncthreads();

    f32x4 acc[4][4];
#pragma unroll
    for (int m = 0; m < 4; ++m)
#pragma unroll
        for (int n = 0; n < 4; ++n) acc[m][n] = f32x4{0.f, 0.f, 0.f, 0.f};

#pragma unroll
    for (int ky = 0; ky < 3; ++ky)
#pragma unroll
    for (int kx = 0; kx < 3; ++kx) {
        const int t = ky * 3 + kx;
#pragma unroll
        for (int kk = 0; kk < 2; ++kk) {
            bf16x8 a[4];
            const unsigned short* wbase = Wg + kk * 18432 + ls * 4608 + t * 512 + lx * 8;
#pragma unroll
            for (int m = 0; m < 4; ++m)
                a[m] = *(const bf16x8*)(wbase + m * 128);
            const unsigned short* ibase =
                smIn + ((kk * 4 + ls) * 324 + (4 * w + ky) * 18 + lx + kx) * 8;
#pragma unroll
            for (int n = 0; n < 4; ++n) {
                bf16x8 bf = *(const bf16x8*)(ibase + n * 144);
#pragma unroll
                for (int m = 0; m < 4; ++m)
                    acc[m][n] = __builtin_amdgcn_mfma_f32_16x16x32_bf16(
                        a[m], bf, acc[m][n], 0, 0, 0);
            }
        }
    }

    // epilogue: D col = lx -> x, row = ls*4+r (+16m) -> co
    const int y0 = by + 4 * w;
    float gs[4], gm[4];
    if constexpr (RGB || COMP) {
#pragma unroll
        for (int n = 0; n < 4; ++n) { gs[n] = 0.f; gm[n] = -1e30f; }
    }
#pragma unroll
    for (int m = 0; m < 4; ++m) {
        float4 rw4;
        if constexpr (RGB) rw4 = *(const float4*)(gw + 16 * m + ls * 4);
        const float rwf[4] = {RGB ? rw4.x : 0.f, RGB ? rw4.y : 0.f,
                              RGB ? rw4.z : 0.f, RGB ? rw4.w : 0.f};
        float bv[4] = {0.f, 0.f, 0.f, 0.f};
        if constexpr (BIAS) {
            float4 b4 = *(const float4*)(bias + 16 * m + ls * 4);
            bv[0] = b4.x; bv[1] = b4.y; bv[2] = b4.z; bv[3] = b4.w;
        }
        const size_t rowb = (size_t)(b * 8 + m * 2 + (ls >> 1)) * HW;
        const int j0 = (ls & 1) * 4;
#pragma unroll
        for (int n = 0; n < 4; ++n) {
            const size_t pofs = rowb + (size_t)(y0 + n) * Wn + bx + lx;
            u32x2 rin;
            if constexpr (ADD_INPUT) rin = *(const u32x2*)(in + pofs * 8 + j0);
            float vr[4];
#pragma unroll
            for (int r = 0; r < 4; ++r) {
                float v = acc[m][n][r] + bv[r];
                if constexpr (RELU) v = fmaxf(v, 0.f);
                if constexpr (ADD_INPUT) v += bfhalf(rin[r >> 1], r & 1);
                vr[r] = v;
                if constexpr (RGB) gs[n] = fmaf(rwf[r], v, gs[n]);
                if constexpr (COMP) { gm[n] = fmaxf(gm[n], v); gs[n] += v; }
            }
            if constexpr (STORE) {
                u32x2 pk;
                pk[0] = (unsigned)f2bf(vr[0]) | ((unsigned)f2bf(vr[1]) << 16);
                pk[1] = (unsigned)f2bf(vr[2]) | ((unsigned)f2bf(vr[3]) << 16);
                *(u32x2*)(out + pofs * 8 + j0) = pk;
            }
        }
    }
    if constexpr (RGB) {
#pragma unroll
        for (int n = 0; n < 4; ++n) {
            float s = gs[n];
            s += __shfl_xor(s, 16);
            s += __shfl_xor(s, 32);
            if (ls == 0)
                gout[(size_t)b * HW + (size_t)(y0 + n) * Wn + bx + lx] = s + gb[0];
        }
    }
    if constexpr (COMP) {
#pragma unroll
        for (int n = 0; n < 4; ++n) {
            float s = gs[n], mx = gm[n];
            s += __shfl_xor(s, 16);
            s += __shfl_xor(s, 32);
            mx = fmaxf(mx, __shfl_xor(mx, 16));
            mx = fmaxf(mx, __shfl_xor(mx, 32));
            if (ls == 0) {
                const size_t o = (size_t)b * 2 * HW + (size_t)(y0 + n) * Wn + bx + lx;
                gout[o]      = mx;
                gout[o + HW] = s * (1.f / 64.f);
            }
        }
    }
}

// ---------------- mean over H,W per (b,oct) from blocked bf16 ----------------
__global__ void mean_hw_blk(const unsigned short* __restrict__ in, float* __restrict__ w0) {
    __shared__ float red[256][8];
    const int bo = blockIdx.x;                 // b*8+oct
    const int tid = threadIdx.x;
    const unsigned short* p = in + (size_t)bo * HW * 8;
    float s[8];
#pragma unroll
    for (int j = 0; j < 8; ++j) s[j] = 0.f;
    for (int it = 0; it < 64; ++it) {
        u32x4 v = *(const u32x4*)(p + (size_t)(tid + it * 256) * 8);
#pragma unroll
        for (int j = 0; j < 8; ++j) s[j] += bfhalf(v[j >> 1], j & 1);
    }
#pragma unroll
    for (int j = 0; j < 8; ++j) red[tid][j] = s[j];
    __syncthreads();
    for (int off = 128; off > 0; off >>= 1) {
        if (tid < off)
#pragma unroll
            for (int j = 0; j < 8; ++j) red[tid][j] += red[tid + off][j];
        __syncthreads();
    }
    if (tid < 8) w0[bo * 8 + tid] = red[0][tid] * (1.f / 16384.f);
}

// ---------------- SE MLP ----------------
__global__ void mlp_k(const float* __restrict__ w0, const float* __restrict__ A1,
                      const float* __restrict__ b1, const float* __restrict__ A2,
                      const float* __restrict__ b2, float* __restrict__ w0s) {
    int b = blockIdx.x, t = threadIdx.x;       // 128 threads
    __shared__ float w0r[64], hid[128];
    if (t < 64) w0r[t] = w0[b * 64 + t];
    __syncthreads();
    float s = b1[t];
    for (int c = 0; c < 64; ++c) s = fmaf(A1[t * 64 + c], w0r[c], s);
    hid[t] = fmaxf(s, 0.f);
    __syncthreads();
    if (t < 64) {
        float s2 = b2[t];
        for (int j = 0; j < 128; ++j) s2 = fmaf(A2[t * 128 + j], hid[j], s2);
        w0s[b * 64 + t] = 1.f / (1.f + expf(-s2));
    }
}

// ---------------- f_b1 = f_blur * (1+w0s) * (1+rgb) -> blocked bf16 ----------------
__global__ void fb1_blk_k(const float* __restrict__ fblur, const float* __restrict__ w0s,
                          const float* __restrict__ rgb, unsigned short* __restrict__ o) {
    int i = blockIdx.x * 256 + threadIdx.x;       // (b, oct, px)
    int px = i & 16383;
    int oct = (i >> 14) & 7;
    int b = i >> 17;
    const float* pb = fblur + (size_t)b * CHW + (size_t)oct * 8 * HW + px;
    const float g = 1.f + rgb[b * HW + px];
    u32x4 pk;
#pragma unroll
    for (int q = 0; q < 4; ++q) {
        float s0 = 1.f + w0s[b * 64 + oct * 8 + 2 * q];
        float s1 = 1.f + w0s[b * 64 + oct * 8 + 2 * q + 1];
        float v0 = pb[(size_t)(2 * q) * HW] * s0 * g;
        float v1 = pb[(size_t)(2 * q + 1) * HW] * s1 * g;
        pk[q] = (unsigned)f2bf(v0) | ((unsigned)f2bf(v1) << 16);
    }
    *(u32x4*)(o + ((size_t)(b * 8 + oct) * HW + px) * 8) = pk;
}

// ---------------- fused dynamic conv (v1 core, blocked I/O) --------------
__global__ __launch_bounds__(256, 2) void dynfused_k(
        const unsigned short* __restrict__ fb1b, const unsigned short* __restrict__ hb,
        const unsigned short* __restrict__ G2p, const float* __restrict__ g2b,
        unsigned short* __restrict__ outb) {
    __shared__ unsigned short smH[8192];       // [oct8][px128][8] 16 KB (reused as [c64][px128] out)
    __shared__ unsigned short smFB[11520];     // [oct8][180][8] 22.5 KB (10x18 patch)
    __shared__ unsigned short smK[2][8192];    // dbuf [r64][px128 swz] 2x16 KB
    const int b  = blockIdx.z;
    const int by = blockIdx.y << 3, bx = blockIdx.x << 4;
    const int tid = threadIdx.x;
    const int lane = tid & 63, w = tid >> 6;
    const int lx = lane & 15, ls = lane >> 4;
    const int wr = w & 1, wc = w >> 1;
    const int px = tid & 127;
    const int chalf = __builtin_amdgcn_readfirstlane(tid >> 7);  // wave-uniform
    const int ty = px >> 4, tx = px & 15;

    // stage h: blocked b128 copy -> [oct][px][8]
#pragma unroll
    for (int it = 0; it < 4; ++it) {
        int i = tid + it * 256;
        int p = i & 127, oct = i >> 7;
        const unsigned short* sp =
            hb + ((size_t)(b * 8 + oct) * HW + (by + (p >> 4)) * Wn + bx + (p & 15)) * 8;
        ((u32x4*)smH)[oct * 128 + p] = *(const u32x4*)sp;
    }
    // stage fb patch: blocked b128 copy, edge-clamped -> [oct][180][8]
    for (int i = tid; i < 1440; i += 256) {
        int oct = i / 180, p = i - oct * 180;
        int pr = p / 18, pc = p - pr * 18;
        int gy = min(max(by + pr - 1, 0), Hn - 1);
        int gx = min(max(bx + pc - 1, 0), Wn - 1);
        ((u32x4*)smFB)[i] =
            *(const u32x4*)(fb1b + ((size_t)(b * 8 + oct) * HW + gy * Wn + gx) * 8);
    }
    __syncthreads();

    float acc[32];
#pragma unroll
    for (int s = 0; s < 32; ++s) acc[s] = 0.f;

#pragma unroll
    for (int chunk = 0; chunk < 9; ++chunk) {
        // GEMM: rows chunk*64 + wr*32 + [0,32), px wc*64 + [0,64), K=64
        f32x4 ka[2][4];
#pragma unroll
        for (int m = 0; m < 2; ++m)
#pragma unroll
            for (int n = 0; n < 4; ++n) ka[m][n] = f32x4{0.f, 0.f, 0.f, 0.f};
#pragma unroll
        for (int kk = 0; kk < 2; ++kk) {
            bf16x8 a[2];
#pragma unroll
            for (int m = 0; m < 2; ++m)
                a[m] = *(const bf16x8*)(G2p +
                        (size_t)(chunk * 64 + wr * 32 + m * 16 + lx) * 64 + kk * 32 + ls * 8);
#pragma unroll
            for (int n = 0; n < 4; ++n) {
                bf16x8 bv = *(const bf16x8*)(smH + ((kk * 4 + ls) * 128 + wc * 64 + n * 16 + lx) * 8);
#pragma unroll
                for (int m = 0; m < 2; ++m)
                    ka[m][n] = __builtin_amdgcn_mfma_f32_16x16x32_bf16(a[m], bv, ka[m][n], 0, 0, 0);
            }
        }
        // epilogue: + g2b, write swizzled smK[chunk&1]
        unsigned short* K = smK[chunk & 1];
#pragma unroll
        for (int m = 0; m < 2; ++m) {
            const float4 bb4 = *(const float4*)(g2b + chunk * 64 + wr * 32 + m * 16 + ls * 4);
            const float bb[4] = {bb4.x, bb4.y, bb4.z, bb4.w};
#pragma unroll
            for (int n = 0; n < 4; ++n) {
                const int pxl = wc * 64 + n * 16 + lx;
                const int base = (pxl >> 1) ^ (ls << 3);
#pragma unroll
                for (int j = 0; j < 4; ++j) {
                    const int rl = wr * 32 + m * 16 + ls * 4 + j;
                    K[rl * 128 + base * 2 + (pxl & 1)] = f2bf(ka[m][n][j] + bb[j]);
                }
            }
        }
        __syncthreads();
        // apply: rows of this chunk whose channel parity == chalf
        const unsigned short* Kr = smK[chunk & 1];
#pragma unroll
        for (int rl = 0; rl < 64; ++rl) {
            const int r = chunk * 64 + rl;         // compile-time
            const int c = r / 9, t = r - c * 9;    // compile-time
            const int s = c >> 1;
            if ((c & 1) == chalf) {
                float kv = bf2f(Kr[rl * 128 +
                                   ((((px >> 1) ^ (((rl >> 2) & 3) << 3)) << 1) | (px & 1))]);
                float pv = bf2f(smFB[((c >> 3) * 180 + (ty + t / 3) * 18 + tx + (t % 3)) * 8 + (c & 7)]);
                acc[s] = fmaf(kv, pv, acc[s]);
            }
        }
    }

    // out = fb1 (center of patch) + dynconv; transpose through smH -> blocked b128
#pragma unroll
    for (int s = 0; s < 32; ++s) {
        const int c = 2 * s + chalf;
        float res = bf2f(smFB[((c >> 3) * 180 + (ty + 1) * 18 + (tx + 1)) * 8 + (c & 7)]);
        smH[c * 128 + px] = f2bf(acc[s] + res);
    }
    __syncthreads();
#pragma unroll
    for (int it = 0; it < 4; ++it) {
        int i = tid + it * 256;
        int p = i & 127, oct = i >> 7;
        u32x4 pk;
#pragma unroll
        for (int q = 0; q < 4; ++q)
            pk[q] = (unsigned)smH[(oct * 8 + 2 * q) * 128 + p] |
                    ((unsigned)smH[(oct * 8 + 2 * q + 1) * 128 + p] << 16);
        *(u32x4*)(outb + ((size_t)(b * 8 + oct) * HW + (by + (p >> 4)) * Wn + bx + (p & 15)) * 8) = pk;
    }
}

// ---------------- final fusion via MFMA: out = Fw @ concat(ev*(1+sc), fb2) -----
__global__ __launch_bounds__(256, 2) void fuse_mfma_k(
        const unsigned short* __restrict__ evb, const float* __restrict__ scale,
        const unsigned short* __restrict__ fb2b, const unsigned short* __restrict__ Fwp,
        float* __restrict__ out) {
    __shared__ unsigned short smF[16384];   // [oct16][px128][8ci] 32 KB
    const int bid = blockIdx.x;
    const int b = bid >> 7, px0 = (bid & 127) << 7;
    const int tid = threadIdx.x;
    const int lane = tid & 63, w = tid >> 6;
    const int lx = lane & 15, ls = lane >> 4;
    const int wr = w & 1, wc = w >> 1;
    const float* sc = scale + b * HW + px0;

#pragma unroll
    for (int it = 0; it < 8; ++it) {
        int slot = tid + it * 256;
        int oct = slot >> 7, pxl = slot & 127;
        u32x4 v;
        if (oct < 8) {
            v = *(const u32x4*)(evb + ((size_t)(b * 8 + oct) * HW + px0 + pxl) * 8);
            float s = 1.f + sc[pxl];
#pragma unroll
            for (int q = 0; q < 4; ++q)
                v[q] = (unsigned)f2bf(bfhalf(v[q], 0) * s) |
                       ((unsigned)f2bf(bfhalf(v[q], 1) * s) << 16);
        } else {
            v = *(const u32x4*)(fb2b + ((size_t)(b * 8 + oct - 8) * HW + px0 + pxl) * 8);
        }
        ((u32x4*)smF)[oct * 128 + pxl] = v;
    }
    __syncthreads();

    f32x4 acc[4][4];
#pragma unroll
    for (int m = 0; m < 4; ++m)
#pragma unroll
        for (int n = 0; n < 4; ++n) acc[m][n] = f32x4{0.f, 0.f, 0.f, 0.f};

#pragma unroll
    for (int kk = 0; kk < 4; ++kk) {
        bf16x8 a[4];
#pragma unroll
        for (int m = 0; m < 4; ++m)
            a[m] = *(const bf16x8*)(Fwp + (size_t)(wr * 64 + m * 16 + lx) * 128 + kk * 32 + ls * 8);
#pragma unroll
        for (int n = 0; n < 4; ++n) {
            bf16x8 bv = *(const bf16x8*)(smF + ((kk * 4 + ls) * 128 + wc * 64 + n * 16 + lx) * 8);
#pragma unroll
            for (int m = 0; m < 4; ++m)
                acc[m][n] = __builtin_amdgcn_mfma_f32_16x16x32_bf16(a[m], bv, acc[m][n], 0, 0, 0);
        }
    }

    const size_t ob = (size_t)b * 2 * CHW + px0 + wc * 64;
#pragma unroll
    for (int m = 0; m < 4; ++m)
#pragma unroll
        for (int n = 0; n < 4; ++n)
#pragma unroll
            for (int j = 0; j < 4; ++j) {
                const int co = wr * 64 + m * 16 + ls * 4 + j;
                out[ob + (size_t)co * HW + n * 16 + lx] = acc[m][n][j];
            }
}

// ---------------- spatial 5x5 conv (2->1, pad 2, zero) + sigmoid ----------------
__global__ void sconv5_k(const float* __restrict__ comp, const float* __restrict__ Ew,
                         const float* __restrict__ eb, float* __restrict__ scale) {
    int id = blockIdx.x * 256 + threadIdx.x;
    int b = id >> 14, p = id & 16383;
    int y = p >> 7, x = p & 127;
    const float* cb = comp + (size_t)b * 2 * HW;
    float acc = eb[0];
#pragma unroll
    for (int ch = 0; ch < 2; ++ch)
#pragma unroll
        for (int ky = 0; ky < 5; ++ky) {
            int gy = y + ky - 2;
            if ((unsigned)gy >= (unsigned)Hn) continue;
#pragma unroll
            for (int kx = 0; kx < 5; ++kx) {
                int gx = x + kx - 2;
                if ((unsigned)gx >= (unsigned)Wn) continue;
                acc = fmaf(Ew[ch * 25 + ky * 5 + kx], cb[ch * HW + gy * Wn + gx], acc);
            }
        }
    scale[id] = 1.f / (1.f + expf(-acc));
}

// ---------------- host launch ----------------
extern "C" void kernel_launch(void* const* d_in, const int* in_sizes, int n_in,
                              void* d_out, int out_size, void* d_ws, size_t ws_size,
                              hipStream_t stream) {
    const float* f_event = (const float*)d_in[0];
    const float* f_blur  = (const float*)d_in[1];
    const float* Wt1 = (const float*)d_in[2];
    const float* Wt2 = (const float*)d_in[3];
    const float* Wt3 = (const float*)d_in[4];
    const float* A1  = (const float*)d_in[5];
    const float* b1  = (const float*)d_in[6];
    const float* A2  = (const float*)d_in[7];
    const float* b2  = (const float*)d_in[8];
    const float* G1  = (const float*)d_in[9];
    const float* g1b = (const float*)d_in[10];
    const float* G2  = (const float*)d_in[11];
    const float* g2b = (const float*)d_in[12];
    const float* Rw  = (const float*)d_in[13];
    const float* rb  = (const float*)d_in[14];
    const float* S1  = (const float*)d_in[15];
    const float* S2  = (const float*)d_in[16];
    const float* Ew  = (const float*)d_in[17];
    const float* eb  = (const float*)d_in[18];
    const float* Fw  = (const float*)d_in[19];
    float* out = (float*)d_out;

    float* ws    = (float*)d_ws;
    float* w0    = ws;                         // 512
    float* w0s   = w0 + 512;                   // 512
    float* rgb   = w0s + 512;                  // 131072
    float* comp  = rgb + Bn * HW;              // 262144
    float* scale = comp + 2 * Bn * HW;         // 131072
    unsigned short* wprep = (unsigned short*)(scale + Bn * HW);  // 6 x 36864
    unsigned short* G2p = wprep + 6 * 36864;                     // 36864
    unsigned short* Fwp = G2p + 36864;                           // 16384
    unsigned short* B0 = Fwp + 16384;          // evblk
    unsigned short* B1 = B0 + NB;              // f0blk -> s1blk
    unsigned short* B2 = B1 + NB;              // t1blk -> fb1blk
    unsigned short* B3 = B2 + NB;              // fusedblk -> fb2blk
    unsigned short* B4 = B3 + NB;              // hblk

    dim3 cgrid(Wn / 16, Hn / 16, Bn);          // 8x8x8

    // 0. weight preps + input blocking
    prep_w_k<<<dim3(144, 6), 256, 0, stream>>>(Wt1, Wt2, Wt3, G1, S1, S2, wprep);
    prep2_k<<<208, 256, 0, stream>>>(G2, Fw, G2p, Fwp);
    pre_blk_k<<<4096, 256, 0, stream>>>(f_event, f_blur, B0, B1);
    // 1. t1 = relu(conv(f0, Wt1))
    conv3x3_blk<true, false, false, false, false, true><<<cgrid, 256, 0, stream>>>(
        B1, wprep + 0 * 36864, nullptr, B2, nullptr, nullptr, nullptr);
    // 2. fused = conv(t1, Wt2)
    conv3x3_blk<false, false, false, false, false, true><<<cgrid, 256, 0, stream>>>(
        B2, wprep + 1 * 36864, nullptr, B3, nullptr, nullptr, nullptr);
    // 3. SE gate
    mean_hw_blk<<<Bn * 8, 256, 0, stream>>>(B3, w0);
    mlp_k<<<Bn, 128, 0, stream>>>(w0, A1, b1, A2, b2, w0s);
    // 4. rgb gate from fused2 = fused + relu(conv(fused, Wt3))  [no store]
    conv3x3_blk<true, false, true, true, false, false><<<cgrid, 256, 0, stream>>>(
        B3, wprep + 2 * 36864, nullptr, nullptr, Rw, rb, rgb);
    // 5. fb1 = f_blur * (1+w0s) * (1+rgb)
    fb1_blk_k<<<4096, 256, 0, stream>>>(f_blur, w0s, rgb, B2);
    // 6. h = relu(conv(ev, G1) + g1b)
    conv3x3_blk<true, true, false, false, false, true><<<cgrid, 256, 0, stream>>>(
        B0, wprep + 3 * 36864, g1b, B4, nullptr, nullptr, nullptr);
    // 7. fb2 = fb1 + dynconv(fb1, kern(h))
    dynfused_k<<<dim3(8, 16, Bn), 256, 0, stream>>>(B2, B4, G2p, g2b, B3);
    // 8. sa chain: s1 = relu(conv(ev, S1)); comp from conv(s1, S2) epilogue
    conv3x3_blk<true, false, false, false, false, true><<<cgrid, 256, 0, stream>>>(
        B0, wprep + 4 * 36864, nullptr, B1, nullptr, nullptr, nullptr);
    conv3x3_blk<false, false, false, false, true, false><<<cgrid, 256, 0, stream>>>(
        B1, wprep + 5 * 36864, nullptr, nullptr, nullptr, nullptr, comp);
    // 9. scale_e = sigmoid(conv5x5(comp))
    sconv5_k<<<Bn * HW / 256, 256, 0, stream>>>(comp, Ew, eb, scale);
    // 10. out = Fw @ concat(ev*(1+scale_e), fb2)
    fuse_mfma_k<<<Bn * HW / 128, 256, 0, stream>>>(B0, scale, B3, Fwp, out);
}

// Round 9
// 250.915 us; speedup vs baseline: 12.5654x; 1.0191x over previous
//
#include <hip/hip_runtime.h>
#include <math.h>

constexpr int Bn = 8, Cn = 64, Hn = 128, Wn = 128;
constexpr int HW  = Hn * Wn;      // 16384
constexpr int CHW = Cn * HW;      // 1048576
constexpr size_t NB = (size_t)Bn * CHW;   // elems per blocked tensor

typedef float  f32x4  __attribute__((ext_vector_type(4)));
typedef __bf16 bf16x8 __attribute__((ext_vector_type(8)));
typedef unsigned int u32x4 __attribute__((ext_vector_type(4)));
typedef unsigned int u32x2 __attribute__((ext_vector_type(2)));

static __device__ __forceinline__ unsigned short f2bf(float f) {
    unsigned u = __builtin_bit_cast(unsigned, f);
    u = (u + 0x7FFF + ((u >> 16) & 1)) >> 16;
    return (unsigned short)u;
}
static __device__ __forceinline__ float bf2f(unsigned short v) {
    unsigned u = (unsigned)v << 16;
    return __builtin_bit_cast(float, u);
}
static __device__ __forceinline__ float bfhalf(unsigned u, int hi) {
    unsigned r = hi ? (u & 0xffff0000u) : (u << 16);
    return __builtin_bit_cast(float, r);
}

// ---------------- weight prep: OIHW fp32 -> [kk][s][t][co][8cj] bf16 ----------------
__global__ void prep_w_k(const float* __restrict__ W0, const float* __restrict__ W1,
                         const float* __restrict__ W2, const float* __restrict__ W3,
                         const float* __restrict__ W4, const float* __restrict__ W5,
                         unsigned short* __restrict__ dst) {
    int i = blockIdx.x * 256 + threadIdx.x;
    if (i >= 36864) return;
    const float* W = W0;
    switch (blockIdx.y) {
        case 1: W = W1; break; case 2: W = W2; break;
        case 3: W = W3; break; case 4: W = W4; break; case 5: W = W5; break;
        default: break;
    }
    int cj = i & 7;
    int rest = i >> 3;
    int co = rest & 63;
    rest >>= 6;              // (kk*4+s)*9 + t
    int t  = rest % 9;
    int hs = rest / 9;       // 0..7
    int ci = hs * 8 + cj;
    dst[(size_t)blockIdx.y * 36864 + i] = f2bf(W[(co * 64 + ci) * 9 + t]);
}

// ---------------- prep2: G2 [576x64] and Fw [128x128] -> bf16 row-major --------
__global__ void prep2_k(const float* __restrict__ G2, const float* __restrict__ Fw,
                        unsigned short* __restrict__ G2p, unsigned short* __restrict__ Fwp) {
    int i = blockIdx.x * 256 + threadIdx.x;
    if (i < 36864) G2p[i] = f2bf(G2[i]);
    else if (i < 36864 + 16384) Fwp[i - 36864] = f2bf(Fw[i - 36864]);
}

// ---------------- pre: f_event -> evblk; f_event+f_blur -> f0blk (blocked bf16) ----
__global__ void pre_blk_k(const float* __restrict__ fe, const float* __restrict__ fb,
                          unsigned short* __restrict__ evb, unsigned short* __restrict__ f0b) {
    int i = blockIdx.x * 256 + threadIdx.x;       // (b, oct, px)
    int px = i & 16383;
    int oct = (i >> 14) & 7;
    int b = i >> 17;
    const float* pe = fe + (size_t)b * CHW + (size_t)oct * 8 * HW + px;
    const float* pb = fb + (size_t)b * CHW + (size_t)oct * 8 * HW + px;
    u32x4 ev, f0;
#pragma unroll
    for (int q = 0; q < 4; ++q) {
        float e0 = pe[(size_t)(2 * q) * HW],     b0 = pb[(size_t)(2 * q) * HW];
        float e1 = pe[(size_t)(2 * q + 1) * HW], b1 = pb[(size_t)(2 * q + 1) * HW];
        ev[q] = (unsigned)f2bf(e0) | ((unsigned)f2bf(e1) << 16);
        f0[q] = (unsigned)f2bf(e0 + b0) | ((unsigned)f2bf(e1 + b1) << 16);
    }
    const size_t o = ((size_t)(b * 8 + oct) * HW + px) * 8;
    *(u32x4*)(evb + o) = ev;
    *(u32x4*)(f0b + o) = f0;
}

// ---------------- conv3x3 via MFMA, blocked bf16 in/out, zero pad=1 ----------------
template<bool RELU, bool BIAS, bool ADD_INPUT, bool RGB, bool COMP, bool STORE>
__global__ __launch_bounds__(256, 3) void conv3x3_blk(
        const unsigned short* __restrict__ in, const unsigned short* __restrict__ Wg,
        const float* __restrict__ bias, unsigned short* __restrict__ out,
        const float* __restrict__ gw, const float* __restrict__ gb,
        float* __restrict__ gout) {
    __shared__ unsigned short smIn[20736];   // 8 x 324 x 8 = 40.5 KB
    const int b  = blockIdx.z;
    const int by = blockIdx.y << 4, bx = blockIdx.x << 4;
    const int tid = threadIdx.x;
    const int lane = tid & 63, w = tid >> 6;
    const int lx = lane & 15, ls = lane >> 4;

    for (int idx = tid; idx < 2592; idx += 256) {
        int oct = idx / 324;
        int p   = idx - oct * 324;
        int yy = p / 18, xx = p - yy * 18;
        int gy = by + yy - 1, gx = bx + xx - 1;
        u32x4 v = u32x4{0u, 0u, 0u, 0u};
        if ((unsigned)gy < (unsigned)Hn && (unsigned)gx < (unsigned)Wn)
            v = *(const u32x4*)(in + ((size_t)(b * 8 + oct) * HW + gy * Wn + gx) * 8);
        *(u32x4*)(smIn + idx * 8) = v;
    }
    __syncthreads();

    f32x4 acc[4][4];
#pragma unroll
    for (int m = 0; m < 4; ++m)
#pragma unroll
        for (int n = 0; n < 4; ++n) acc[m][n] = f32x4{0.f, 0.f, 0.f, 0.f};

#pragma unroll
    for (int ky = 0; ky < 3; ++ky)
#pragma unroll
    for (int kx = 0; kx < 3; ++kx) {
        const int t = ky * 3 + kx;
#pragma unroll
        for (int kk = 0; kk < 2; ++kk) {
            bf16x8 a[4];
            const unsigned short* wbase = Wg + kk * 18432 + ls * 4608 + t * 512 + lx * 8;
#pragma unroll
            for (int m = 0; m < 4; ++m)
                a[m] = *(const bf16x8*)(wbase + m * 128);
            const unsigned short* ibase =
                smIn + ((kk * 4 + ls) * 324 + (4 * w + ky) * 18 + lx + kx) * 8;
#pragma unroll
            for (int n = 0; n < 4; ++n) {
                bf16x8 bf = *(const bf16x8*)(ibase + n * 144);
#pragma unroll
                for (int m = 0; m < 4; ++m)
                    acc[m][n] = __builtin_amdgcn_mfma_f32_16x16x32_bf16(
                        a[m], bf, acc[m][n], 0, 0, 0);
            }
        }
    }

    // epilogue: D col = lx -> x, row = ls*4+r (+16m) -> co
    const int y0 = by + 4 * w;
    float gs[4], gm[4];
    if constexpr (RGB || COMP) {
#pragma unroll
        for (int n = 0; n < 4; ++n) { gs[n] = 0.f; gm[n] = -1e30f; }
    }
#pragma unroll
    for (int m = 0; m < 4; ++m) {
        float4 rw4;
        if constexpr (RGB) rw4 = *(const float4*)(gw + 16 * m + ls * 4);
        const float rwf[4] = {RGB ? rw4.x : 0.f, RGB ? rw4.y : 0.f,
                              RGB ? rw4.z : 0.f, RGB ? rw4.w : 0.f};
        float bv[4] = {0.f, 0.f, 0.f, 0.f};
        if constexpr (BIAS) {
            float4 b4 = *(const float4*)(bias + 16 * m + ls * 4);
            bv[0] = b4.x; bv[1] = b4.y; bv[2] = b4.z; bv[3] = b4.w;
        }
        const size_t rowb = (size_t)(b * 8 + m * 2 + (ls >> 1)) * HW;
        const int j0 = (ls & 1) * 4;
#pragma unroll
        for (int n = 0; n < 4; ++n) {
            const size_t pofs = rowb + (size_t)(y0 + n) * Wn + bx + lx;
            u32x2 rin;
            if constexpr (ADD_INPUT) rin = *(const u32x2*)(in + pofs * 8 + j0);
            float vr[4];
#pragma unroll
            for (int r = 0; r < 4; ++r) {
                float v = acc[m][n][r] + bv[r];
                if constexpr (RELU) v = fmaxf(v, 0.f);
                if constexpr (ADD_INPUT) v += bfhalf(rin[r >> 1], r & 1);
                vr[r] = v;
                if constexpr (RGB) gs[n] = fmaf(rwf[r], v, gs[n]);
                if constexpr (COMP) { gm[n] = fmaxf(gm[n], v); gs[n] += v; }
            }
            if constexpr (STORE) {
                u32x2 pk;
                pk[0] = (unsigned)f2bf(vr[0]) | ((unsigned)f2bf(vr[1]) << 16);
                pk[1] = (unsigned)f2bf(vr[2]) | ((unsigned)f2bf(vr[3]) << 16);
                *(u32x2*)(out + pofs * 8 + j0) = pk;
            }
        }
    }
    if constexpr (RGB) {
#pragma unroll
        for (int n = 0; n < 4; ++n) {
            float s = gs[n];
            s += __shfl_xor(s, 16);
            s += __shfl_xor(s, 32);
            if (ls == 0)
                gout[(size_t)b * HW + (size_t)(y0 + n) * Wn + bx + lx] = s + gb[0];
        }
    }
    if constexpr (COMP) {
#pragma unroll
        for (int n = 0; n < 4; ++n) {
            float s = gs[n], mx = gm[n];
            s += __shfl_xor(s, 16);
            s += __shfl_xor(s, 32);
            mx = fmaxf(mx, __shfl_xor(mx, 16));
            mx = fmaxf(mx, __shfl_xor(mx, 32));
            if (ls == 0) {
                const size_t o = (size_t)b * 2 * HW + (size_t)(y0 + n) * Wn + bx + lx;
                gout[o]      = mx;
                gout[o + HW] = s * (1.f / 64.f);
            }
        }
    }
}

// ---------------- dual conv: two weight sets over the same input (G1 & S1) ----------
// grid z = 16: b = z&7, sel = z>>3. sel 0: relu(conv+g1b) -> out0; sel 1: relu(conv) -> out1.
__global__ __launch_bounds__(256, 3) void conv3x3_dual_blk(
        const unsigned short* __restrict__ in, const unsigned short* __restrict__ W0,
        const unsigned short* __restrict__ W1, const float* __restrict__ bias0,
        unsigned short* __restrict__ out0, unsigned short* __restrict__ out1) {
    __shared__ unsigned short smIn[20736];
    const int z = blockIdx.z;
    const int b = z & 7, sel = z >> 3;
    const unsigned short* Wg = sel ? W1 : W0;
    unsigned short* out = sel ? out1 : out0;
    const int by = blockIdx.y << 4, bx = blockIdx.x << 4;
    const int tid = threadIdx.x;
    const int lane = tid & 63, w = tid >> 6;
    const int lx = lane & 15, ls = lane >> 4;

    for (int idx = tid; idx < 2592; idx += 256) {
        int oct = idx / 324;
        int p   = idx - oct * 324;
        int yy = p / 18, xx = p - yy * 18;
        int gy = by + yy - 1, gx = bx + xx - 1;
        u32x4 v = u32x4{0u, 0u, 0u, 0u};
        if ((unsigned)gy < (unsigned)Hn && (unsigned)gx < (unsigned)Wn)
            v = *(const u32x4*)(in + ((size_t)(b * 8 + oct) * HW + gy * Wn + gx) * 8);
        *(u32x4*)(smIn + idx * 8) = v;
    }
    __syncthreads();

    f32x4 acc[4][4];
#pragma unroll
    for (int m = 0; m < 4; ++m)
#pragma unroll
        for (int n = 0; n < 4; ++n) acc[m][n] = f32x4{0.f, 0.f, 0.f, 0.f};

#pragma unroll
    for (int ky = 0; ky < 3; ++ky)
#pragma unroll
    for (int kx = 0; kx < 3; ++kx) {
        const int t = ky * 3 + kx;
#pragma unroll
        for (int kk = 0; kk < 2; ++kk) {
            bf16x8 a[4];
            const unsigned short* wbase = Wg + kk * 18432 + ls * 4608 + t * 512 + lx * 8;
#pragma unroll
            for (int m = 0; m < 4; ++m)
                a[m] = *(const bf16x8*)(wbase + m * 128);
            const unsigned short* ibase =
                smIn + ((kk * 4 + ls) * 324 + (4 * w + ky) * 18 + lx + kx) * 8;
#pragma unroll
            for (int n = 0; n < 4; ++n) {
                bf16x8 bf = *(const bf16x8*)(ibase + n * 144);
#pragma unroll
                for (int m = 0; m < 4; ++m)
                    acc[m][n] = __builtin_amdgcn_mfma_f32_16x16x32_bf16(
                        a[m], bf, acc[m][n], 0, 0, 0);
            }
        }
    }

    const int y0 = by + 4 * w;
#pragma unroll
    for (int m = 0; m < 4; ++m) {
        float bv[4] = {0.f, 0.f, 0.f, 0.f};
        if (!sel) {
            float4 b4 = *(const float4*)(bias0 + 16 * m + ls * 4);
            bv[0] = b4.x; bv[1] = b4.y; bv[2] = b4.z; bv[3] = b4.w;
        }
        const size_t rowb = (size_t)(b * 8 + m * 2 + (ls >> 1)) * HW;
        const int j0 = (ls & 1) * 4;
#pragma unroll
        for (int n = 0; n < 4; ++n) {
            const size_t pofs = rowb + (size_t)(y0 + n) * Wn + bx + lx;
            float vr[4];
#pragma unroll
            for (int r = 0; r < 4; ++r)
                vr[r] = fmaxf(acc[m][n][r] + bv[r], 0.f);
            u32x2 pk;
            pk[0] = (unsigned)f2bf(vr[0]) | ((unsigned)f2bf(vr[1]) << 16);
            pk[1] = (unsigned)f2bf(vr[2]) | ((unsigned)f2bf(vr[3]) << 16);
            *(u32x2*)(out + pofs * 8 + j0) = pk;
        }
    }
}

// ---------------- mean over H,W per (b,oct) from blocked bf16 ----------------
__global__ void mean_hw_blk(const unsigned short* __restrict__ in, float* __restrict__ w0) {
    __shared__ float red[256][8];
    const int bo = blockIdx.x;                 // b*8+oct
    const int tid = threadIdx.x;
    const unsigned short* p = in + (size_t)bo * HW * 8;
    float s[8];
#pragma unroll
    for (int j = 0; j < 8; ++j) s[j] = 0.f;
    for (int it = 0; it < 64; ++it) {
        u32x4 v = *(const u32x4*)(p + (size_t)(tid + it * 256) * 8);
#pragma unroll
        for (int j = 0; j < 8; ++j) s[j] += bfhalf(v[j >> 1], j & 1);
    }
#pragma unroll
    for (int j = 0; j < 8; ++j) red[tid][j] = s[j];
    __syncthreads();
    for (int off = 128; off > 0; off >>= 1) {
        if (tid < off)
#pragma unroll
            for (int j = 0; j < 8; ++j) red[tid][j] += red[tid + off][j];
        __syncthreads();
    }
    if (tid < 8) w0[bo * 8 + tid] = red[0][tid] * (1.f / 16384.f);
}

// ---------------- SE MLP ----------------
__global__ void mlp_k(const float* __restrict__ w0, const float* __restrict__ A1,
                      const float* __restrict__ b1, const float* __restrict__ A2,
                      const float* __restrict__ b2, float* __restrict__ w0s) {
    int b = blockIdx.x, t = threadIdx.x;       // 128 threads
    __shared__ float w0r[64], hid[128];
    if (t < 64) w0r[t] = w0[b * 64 + t];
    __syncthreads();
    float s = b1[t];
    for (int c = 0; c < 64; ++c) s = fmaf(A1[t * 64 + c], w0r[c], s);
    hid[t] = fmaxf(s, 0.f);
    __syncthreads();
    if (t < 64) {
        float s2 = b2[t];
        for (int j = 0; j < 128; ++j) s2 = fmaf(A2[t * 128 + j], hid[j], s2);
        w0s[b * 64 + t] = 1.f / (1.f + expf(-s2));
    }
}

// ---------------- f_b1 = f_blur * (1+w0s) * (1+rgb) -> blocked bf16 ----------------
__global__ void fb1_blk_k(const float* __restrict__ fblur, const float* __restrict__ w0s,
                          const float* __restrict__ rgb, unsigned short* __restrict__ o) {
    int i = blockIdx.x * 256 + threadIdx.x;       // (b, oct, px)
    int px = i & 16383;
    int oct = (i >> 14) & 7;
    int b = i >> 17;
    const float* pb = fblur + (size_t)b * CHW + (size_t)oct * 8 * HW + px;
    const float g = 1.f + rgb[b * HW + px];
    u32x4 pk;
#pragma unroll
    for (int q = 0; q < 4; ++q) {
        float s0 = 1.f + w0s[b * 64 + oct * 8 + 2 * q];
        float s1 = 1.f + w0s[b * 64 + oct * 8 + 2 * q + 1];
        float v0 = pb[(size_t)(2 * q) * HW] * s0 * g;
        float v1 = pb[(size_t)(2 * q + 1) * HW] * s1 * g;
        pk[q] = (unsigned)f2bf(v0) | ((unsigned)f2bf(v1) << 16);
    }
    *(u32x4*)(o + ((size_t)(b * 8 + oct) * HW + px) * 8) = pk;
}

// ---------------- fused dynamic conv (v1 core, blocked I/O, scalar smFB) ----------
__global__ __launch_bounds__(256, 2) void dynfused_k(
        const unsigned short* __restrict__ fb1b, const unsigned short* __restrict__ hb,
        const unsigned short* __restrict__ G2p, const float* __restrict__ g2b,
        unsigned short* __restrict__ outb) {
    __shared__ unsigned short smH[8192];       // [oct8][px128][8] 16 KB (reused as [c64][px128] out)
    __shared__ unsigned short smFB[11520];     // [c64][180] 22.5 KB (10x18 patch, scalar)
    __shared__ unsigned short smK[2][8192];    // dbuf [r64][px128 swz] 2x16 KB
    const int b  = blockIdx.z;
    const int by = blockIdx.y << 3, bx = blockIdx.x << 4;
    const int tid = threadIdx.x;
    const int lane = tid & 63, w = tid >> 6;
    const int lx = lane & 15, ls = lane >> 4;
    const int wr = w & 1, wc = w >> 1;
    const int px = tid & 127;
    const int chalf = __builtin_amdgcn_readfirstlane(tid >> 7);  // wave-uniform
    const int ty = px >> 4, tx = px & 15;

    // stage h: blocked b128 copy -> [oct][px][8]
#pragma unroll
    for (int it = 0; it < 4; ++it) {
        int i = tid + it * 256;
        int p = i & 127, oct = i >> 7;
        const unsigned short* sp =
            hb + ((size_t)(b * 8 + oct) * HW + (by + (p >> 4)) * Wn + bx + (p & 15)) * 8;
        ((u32x4*)smH)[oct * 128 + p] = *(const u32x4*)sp;
    }
    // stage fb patch: blocked b128 load, scatter to scalar [c][180] (conflict-free apply)
    for (int i = tid; i < 1440; i += 256) {
        int oct = i / 180, p = i - oct * 180;
        int pr = p / 18, pc = p - pr * 18;
        int gy = min(max(by + pr - 1, 0), Hn - 1);
        int gx = min(max(bx + pc - 1, 0), Wn - 1);
        u32x4 v = *(const u32x4*)(fb1b + ((size_t)(b * 8 + oct) * HW + gy * Wn + gx) * 8);
#pragma unroll
        for (int j = 0; j < 8; ++j)
            smFB[(oct * 8 + j) * 180 + p] =
                (unsigned short)(v[j >> 1] >> ((j & 1) * 16));
    }
    __syncthreads();

    float acc[32];
#pragma unroll
    for (int s = 0; s < 32; ++s) acc[s] = 0.f;

#pragma unroll
    for (int chunk = 0; chunk < 9; ++chunk) {
        // GEMM: rows chunk*64 + wr*32 + [0,32), px wc*64 + [0,64), K=64
        f32x4 ka[2][4];
#pragma unroll
        for (int m = 0; m < 2; ++m)
#pragma unroll
            for (int n = 0; n < 4; ++n) ka[m][n] = f32x4{0.f, 0.f, 0.f, 0.f};
#pragma unroll
        for (int kk = 0; kk < 2; ++kk) {
            bf16x8 a[2];
#pragma unroll
            for (int m = 0; m < 2; ++m)
                a[m] = *(const bf16x8*)(G2p +
                        (size_t)(chunk * 64 + wr * 32 + m * 16 + lx) * 64 + kk * 32 + ls * 8);
#pragma unroll
            for (int n = 0; n < 4; ++n) {
                bf16x8 bv = *(const bf16x8*)(smH + ((kk * 4 + ls) * 128 + wc * 64 + n * 16 + lx) * 8);
#pragma unroll
                for (int m = 0; m < 2; ++m)
                    ka[m][n] = __builtin_amdgcn_mfma_f32_16x16x32_bf16(a[m], bv, ka[m][n], 0, 0, 0);
            }
        }
        // epilogue: + g2b, write swizzled smK[chunk&1]
        unsigned short* K = smK[chunk & 1];
#pragma unroll
        for (int m = 0; m < 2; ++m) {
            const float4 bb4 = *(const float4*)(g2b + chunk * 64 + wr * 32 + m * 16 + ls * 4);
            const float bb[4] = {bb4.x, bb4.y, bb4.z, bb4.w};
#pragma unroll
            for (int n = 0; n < 4; ++n) {
                const int pxl = wc * 64 + n * 16 + lx;
                const int base = (pxl >> 1) ^ (ls << 3);
#pragma unroll
                for (int j = 0; j < 4; ++j) {
                    const int rl = wr * 32 + m * 16 + ls * 4 + j;
                    K[rl * 128 + base * 2 + (pxl & 1)] = f2bf(ka[m][n][j] + bb[j]);
                }
            }
        }
        __syncthreads();
        // apply: rows of this chunk whose channel parity == chalf
        const unsigned short* Kr = smK[chunk & 1];
#pragma unroll
        for (int rl = 0; rl < 64; ++rl) {
            const int r = chunk * 64 + rl;         // compile-time
            const int c = r / 9, t = r - c * 9;    // compile-time
            const int s = c >> 1;
            if ((c & 1) == chalf) {
                float kv = bf2f(Kr[rl * 128 +
                                   ((((px >> 1) ^ (((rl >> 2) & 3) << 3)) << 1) | (px & 1))]);
                float pv = bf2f(smFB[c * 180 + (ty + t / 3) * 18 + tx + (t % 3)]);
                acc[s] = fmaf(kv, pv, acc[s]);
            }
        }
    }

    // out = fb1 (center of patch) + dynconv; transpose through smH -> blocked b128
#pragma unroll
    for (int s = 0; s < 32; ++s) {
        const int c = 2 * s + chalf;
        float res = bf2f(smFB[c * 180 + (ty + 1) * 18 + (tx + 1)]);
        smH[c * 128 + px] = f2bf(acc[s] + res);
    }
    __syncthreads();
#pragma unroll
    for (int it = 0; it < 4; ++it) {
        int i = tid + it * 256;
        int p = i & 127, oct = i >> 7;
        u32x4 pk;
#pragma unroll
        for (int q = 0; q < 4; ++q)
            pk[q] = (unsigned)smH[(oct * 8 + 2 * q) * 128 + p] |
                    ((unsigned)smH[(oct * 8 + 2 * q + 1) * 128 + p] << 16);
        *(u32x4*)(outb + ((size_t)(b * 8 + oct) * HW + (by + (p >> 4)) * Wn + bx + (p & 15)) * 8) = pk;
    }
}

// ---------------- final fusion via MFMA: out = Fw @ concat(ev*(1+sc), fb2) -----
__global__ __launch_bounds__(256, 2) void fuse_mfma_k(
        const unsigned short* __restrict__ evb, const float* __restrict__ scale,
        const unsigned short* __restrict__ fb2b, const unsigned short* __restrict__ Fwp,
        float* __restrict__ out) {
    __shared__ unsigned short smF[16384];   // [oct16][px128][8ci] 32 KB
    const int bid = blockIdx.x;
    const int b = bid >> 7, px0 = (bid & 127) << 7;
    const int tid = threadIdx.x;
    const int lane = tid & 63, w = tid >> 6;
    const int lx = lane & 15, ls = lane >> 4;
    const int wr = w & 1, wc = w >> 1;
    const float* sc = scale + b * HW + px0;

#pragma unroll
    for (int it = 0; it < 8; ++it) {
        int slot = tid + it * 256;
        int oct = slot >> 7, pxl = slot & 127;
        u32x4 v;
        if (oct < 8) {
            v = *(const u32x4*)(evb + ((size_t)(b * 8 + oct) * HW + px0 + pxl) * 8);
            float s = 1.f + sc[pxl];
#pragma unroll
            for (int q = 0; q < 4; ++q)
                v[q] = (unsigned)f2bf(bfhalf(v[q], 0) * s) |
                       ((unsigned)f2bf(bfhalf(v[q], 1) * s) << 16);
        } else {
            v = *(const u32x4*)(fb2b + ((size_t)(b * 8 + oct - 8) * HW + px0 + pxl) * 8);
        }
        ((u32x4*)smF)[oct * 128 + pxl] = v;
    }
    __syncthreads();

    f32x4 acc[4][4];
#pragma unroll
    for (int m = 0; m < 4; ++m)
#pragma unroll
        for (int n = 0; n < 4; ++n) acc[m][n] = f32x4{0.f, 0.f, 0.f, 0.f};

#pragma unroll
    for (int kk = 0; kk < 4; ++kk) {
        bf16x8 a[4];
#pragma unroll
        for (int m = 0; m < 4; ++m)
            a[m] = *(const bf16x8*)(Fwp + (size_t)(wr * 64 + m * 16 + lx) * 128 + kk * 32 + ls * 8);
#pragma unroll
        for (int n = 0; n < 4; ++n) {
            bf16x8 bv = *(const bf16x8*)(smF + ((kk * 4 + ls) * 128 + wc * 64 + n * 16 + lx) * 8);
#pragma unroll
            for (int m = 0; m < 4; ++m)
                acc[m][n] = __builtin_amdgcn_mfma_f32_16x16x32_bf16(a[m], bv, acc[m][n], 0, 0, 0);
        }
    }

    const size_t ob = (size_t)b * 2 * CHW + px0 + wc * 64;
#pragma unroll
    for (int m = 0; m < 4; ++m)
#pragma unroll
        for (int n = 0; n < 4; ++n)
#pragma unroll
            for (int j = 0; j < 4; ++j) {
                const int co = wr * 64 + m * 16 + ls * 4 + j;
                out[ob + (size_t)co * HW + n * 16 + lx] = acc[m][n][j];
            }
}

// ---------------- spatial 5x5 conv (2->1, pad 2, zero) + sigmoid ----------------
__global__ void sconv5_k(const float* __restrict__ comp, const float* __restrict__ Ew,
                         const float* __restrict__ eb, float* __restrict__ scale) {
    int id = blockIdx.x * 256 + threadIdx.x;
    int b = id >> 14, p = id & 16383;
    int y = p >> 7, x = p & 127;
    const float* cb = comp + (size_t)b * 2 * HW;
    float acc = eb[0];
#pragma unroll
    for (int ch = 0; ch < 2; ++ch)
#pragma unroll
        for (int ky = 0; ky < 5; ++ky) {
            int gy = y + ky - 2;
            if ((unsigned)gy >= (unsigned)Hn) continue;
#pragma unroll
            for (int kx = 0; kx < 5; ++kx) {
                int gx = x + kx - 2;
                if ((unsigned)gx >= (unsigned)Wn) continue;
                acc = fmaf(Ew[ch * 25 + ky * 5 + kx], cb[ch * HW + gy * Wn + gx], acc);
            }
        }
    scale[id] = 1.f / (1.f + expf(-acc));
}

// ---------------- host launch ----------------
extern "C" void kernel_launch(void* const* d_in, const int* in_sizes, int n_in,
                              void* d_out, int out_size, void* d_ws, size_t ws_size,
                              hipStream_t stream) {
    const float* f_event = (const float*)d_in[0];
    const float* f_blur  = (const float*)d_in[1];
    const float* Wt1 = (const float*)d_in[2];
    const float* Wt2 = (const float*)d_in[3];
    const float* Wt3 = (const float*)d_in[4];
    const float* A1  = (const float*)d_in[5];
    const float* b1  = (const float*)d_in[6];
    const float* A2  = (const float*)d_in[7];
    const float* b2  = (const float*)d_in[8];
    const float* G1  = (const float*)d_in[9];
    const float* g1b = (const float*)d_in[10];
    const float* G2  = (const float*)d_in[11];
    const float* g2b = (const float*)d_in[12];
    const float* Rw  = (const float*)d_in[13];
    const float* rb  = (const float*)d_in[14];
    const float* S1  = (const float*)d_in[15];
    const float* S2  = (const float*)d_in[16];
    const float* Ew  = (const float*)d_in[17];
    const float* eb  = (const float*)d_in[18];
    const float* Fw  = (const float*)d_in[19];
    float* out = (float*)d_out;

    float* ws    = (float*)d_ws;
    float* w0    = ws;                         // 512
    float* w0s   = w0 + 512;                   // 512
    float* rgb   = w0s + 512;                  // 131072
    float* comp  = rgb + Bn * HW;              // 262144
    float* scale = comp + 2 * Bn * HW;         // 131072
    unsigned short* wprep = (unsigned short*)(scale + Bn * HW);  // 6 x 36864
    unsigned short* G2p = wprep + 6 * 36864;                     // 36864
    unsigned short* Fwp = G2p + 36864;                           // 16384
    unsigned short* B0 = Fwp + 16384;          // evblk
    unsigned short* B1 = B0 + NB;              // f0blk -> s1blk
    unsigned short* B2 = B1 + NB;              // t1blk -> fb1blk
    unsigned short* B3 = B2 + NB;              // fusedblk -> fb2blk
    unsigned short* B4 = B3 + NB;              // hblk

    dim3 cgrid(Wn / 16, Hn / 16, Bn);          // 8x8x8
    dim3 cgrid2(Wn / 16, Hn / 16, 2 * Bn);     // dual conv

    // 0. weight preps + input blocking
    prep_w_k<<<dim3(144, 6), 256, 0, stream>>>(Wt1, Wt2, Wt3, G1, S1, S2, wprep);
    prep2_k<<<208, 256, 0, stream>>>(G2, Fw, G2p, Fwp);
    pre_blk_k<<<4096, 256, 0, stream>>>(f_event, f_blur, B0, B1);
    // 1. t1 = relu(conv(f0, Wt1))
    conv3x3_blk<true, false, false, false, false, true><<<cgrid, 256, 0, stream>>>(
        B1, wprep + 0 * 36864, nullptr, B2, nullptr, nullptr, nullptr);
    // 2. fused = conv(t1, Wt2)
    conv3x3_blk<false, false, false, false, false, true><<<cgrid, 256, 0, stream>>>(
        B2, wprep + 1 * 36864, nullptr, B3, nullptr, nullptr, nullptr);
    // 3. SE gate
    mean_hw_blk<<<Bn * 8, 256, 0, stream>>>(B3, w0);
    mlp_k<<<Bn, 128, 0, stream>>>(w0, A1, b1, A2, b2, w0s);
    // 4. rgb gate from fused2 = fused + relu(conv(fused, Wt3))  [no store]
    conv3x3_blk<true, false, true, true, false, false><<<cgrid, 256, 0, stream>>>(
        B3, wprep + 2 * 36864, nullptr, nullptr, Rw, rb, rgb);
    // 5. fb1 = f_blur * (1+w0s) * (1+rgb)
    fb1_blk_k<<<4096, 256, 0, stream>>>(f_blur, w0s, rgb, B2);
    // 6. h = relu(conv(ev, G1) + g1b); s1 = relu(conv(ev, S1))  [dual launch]
    conv3x3_dual_blk<<<cgrid2, 256, 0, stream>>>(
        B0, wprep + 3 * 36864, wprep + 4 * 36864, g1b, B4, B1);
    // 7. fb2 = fb1 + dynconv(fb1, kern(h))
    dynfused_k<<<dim3(8, 16, Bn), 256, 0, stream>>>(B2, B4, G2p, g2b, B3);
    // 8. comp from conv(s1, S2) epilogue
    conv3x3_blk<false, false, false, false, true, false><<<cgrid, 256, 0, stream>>>(
        B1, wprep + 5 * 36864, nullptr, nullptr, nullptr, nullptr, comp);
    // 9. scale_e = sigmoid(conv5x5(comp))
    sconv5_k<<<Bn * HW / 256, 256, 0, stream>>>(comp, Ew, eb, scale);
    // 10. out = Fw @ concat(ev*(1+scale_e), fb2)
    fuse_mfma_k<<<Bn * HW / 128, 256, 0, stream>>>(B0, scale, B3, Fwp, out);
}